// Round 13
// baseline (185.505 us; speedup 1.0000x reference)
//
#include <hip/hip_runtime.h>
#include <math.h>

#define BB 8
#define SS 128
#define NN 129
#define DD 256
#define HH 8
#define LN_EPS 1e-5f

// ws layout (float offsets)
#define OFF_A    0        // a:     [B][S][D]
#define OFF_BPT  262144   // bp_t:  [B][D][S]  (b_ + b_e1, transposed)
#define OFF_CPT  524288   // cp_t:  [B][D][S]  (a + b_ + b_e1, transposed)
#define OFF_VART 786432   // var_t: [B][D][S]  (nv[:,1:,:] transposed)
#define OFF_V    1048576  // v:     [B][N][D]
#define OFF_SQ   1312768  // sq:    [B][H][N]
#define OFF_SK   1321024  // sk:    [B][H][N]
#define OFF_MA   1329280
#define OFF_QA   1330304
#define OFF_MB   1331328
#define OFF_QB   1332352
#define OFF_MC   1333376
#define OFF_QC   1334400
#define OFF_U    1335424  // U: [D][H]
#define OFF_UB   1337472  // ubias: [H]

struct SA {  // part A: k1 work (~40.4 KB)
    float dsc[4][DD];
    float drow[4][DD];
    float4 red[8][4][64];
    float part[24][4];
};
struct SB {  // part B: k2 work (~34 KB)
    float rows[2][DD];
    float4 redq[8][2][64];
    float4 redk[8][2][64];
};
union SMA { SA a; SB b; };

// ============ KA (R4 structure, empirically fastest): proj + stats + U-fold =
__global__ __launch_bounds__(512) void ka_all(
    const float* __restrict__ desc, const float* __restrict__ nv,
    const float* __restrict__ W_gt, const float* __restrict__ b_gt,
    const float* __restrict__ W_e1, const float* __restrict__ b_e1,
    const float* __restrict__ W_q, const float* __restrict__ b_q,
    const float* __restrict__ W_k, const float* __restrict__ b_k,
    const float* __restrict__ W_v, const float* __restrict__ b_v,
    const float* __restrict__ W_e2, const float* __restrict__ b_e2,
    const float* __restrict__ w_attn,
    float* __restrict__ a, float* __restrict__ bp_t, float* __restrict__ cp_t,
    float* __restrict__ var_t, float* __restrict__ v,
    float* __restrict__ sq, float* __restrict__ sk,
    float* __restrict__ ma, float* __restrict__ qa, float* __restrict__ mb,
    float* __restrict__ qb, float* __restrict__ mc, float* __restrict__ qc,
    float* __restrict__ U, float* __restrict__ ubias) {
    __shared__ SMA sm;
    const int bx = blockIdx.x, t = threadIdx.x;

    if (bx < 256) {
        SA& S = sm.a;
        const int b = bx >> 5, s0 = (bx & 31) * 4;
        const int dq = t & 63, kh = t >> 6;
        for (int e = t; e < 4 * DD; e += 512)
            S.dsc[e >> 8][e & 255] = desc[(size_t)(b * SS + s0 + (e >> 8)) * DD + (e & 255)];
        __syncthreads();
        {   // d-gemm, split-k x8
            float4 acc[4];
#pragma unroll
            for (int r = 0; r < 4; r++) acc[r] = make_float4(0.f, 0.f, 0.f, 0.f);
            const int kb = kh * 32;
#pragma unroll 4
            for (int k = kb; k < kb + 32; k++) {
                float4 w = *(const float4*)&W_gt[k * DD + 4 * dq];
#pragma unroll
                for (int r = 0; r < 4; r++) {
                    float x = S.dsc[r][k];
                    acc[r].x = fmaf(x, w.x, acc[r].x); acc[r].y = fmaf(x, w.y, acc[r].y);
                    acc[r].z = fmaf(x, w.z, acc[r].z); acc[r].w = fmaf(x, w.w, acc[r].w);
                }
            }
#pragma unroll
            for (int r = 0; r < 4; r++) S.red[kh][r][dq] = acc[r];
        }
        __syncthreads();
        for (int e = t; e < 4 * DD; e += 512) {
            int r = e >> 8, d2 = e & 255;
            float s = b_gt[d2];
#pragma unroll
            for (int kk = 0; kk < 8; kk++) s += ((const float*)S.red[kk][r])[d2];
            S.drow[r][d2] = s;
        }
        __syncthreads();
        {   // a-gemm
            float4 acc[4];
#pragma unroll
            for (int r = 0; r < 4; r++) acc[r] = make_float4(0.f, 0.f, 0.f, 0.f);
            const int kb = kh * 32;
#pragma unroll 4
            for (int k = kb; k < kb + 32; k++) {
                float4 w = *(const float4*)&W_e1[k * DD + 4 * dq];
#pragma unroll
                for (int r = 0; r < 4; r++) {
                    float x = S.drow[r][k];
                    acc[r].x = fmaf(x, w.x, acc[r].x); acc[r].y = fmaf(x, w.y, acc[r].y);
                    acc[r].z = fmaf(x, w.z, acc[r].z); acc[r].w = fmaf(x, w.w, acc[r].w);
                }
            }
#pragma unroll
            for (int r = 0; r < 4; r++) S.red[kh][r][dq] = acc[r];
        }
        __syncthreads();
        float avf[4];
        if (t < 256) {
            const int d2 = t;
#pragma unroll
            for (int r = 0; r < 4; r++) {
                float s = 0.f;
#pragma unroll
                for (int kk = 0; kk < 8; kk++) s += ((const float*)S.red[kk][r])[d2];
                avf[r] = s;
                a[(size_t)(b * SS + s0 + r) * DD + d2] = s;
            }
        }
        __syncthreads();
        {   // b-gemm
            float4 acc[4];
#pragma unroll
            for (int r = 0; r < 4; r++) acc[r] = make_float4(0.f, 0.f, 0.f, 0.f);
            const int kb = kh * 32;
#pragma unroll 4
            for (int k = kb; k < kb + 32; k++) {
                float4 w = *(const float4*)&W_e1[(DD + k) * DD + 4 * dq];
#pragma unroll
                for (int r = 0; r < 4; r++) {
                    float x = S.drow[r][k];
                    acc[r].x = fmaf(x, w.x, acc[r].x); acc[r].y = fmaf(x, w.y, acc[r].y);
                    acc[r].z = fmaf(x, w.z, acc[r].z); acc[r].w = fmaf(x, w.w, acc[r].w);
                }
            }
#pragma unroll
            for (int r = 0; r < 4; r++) S.red[kh][r][dq] = acc[r];
        }
        __syncthreads();
        if (t < 256) {
            const int d2 = t;
            float bvf[4], cvf[4];
            float be1 = b_e1[d2];
#pragma unroll
            for (int r = 0; r < 4; r++) {
                float s = 0.f;
#pragma unroll
                for (int kk = 0; kk < 8; kk++) s += ((const float*)S.red[kk][r])[d2];
                bvf[r] = s + be1; cvf[r] = avf[r] + bvf[r];
            }
            float4 f4;
            f4.x = bvf[0]; f4.y = bvf[1]; f4.z = bvf[2]; f4.w = bvf[3];
            *(float4*)(bp_t + (size_t)(b * DD + d2) * SS + s0) = f4;
            f4.x = cvf[0]; f4.y = cvf[1]; f4.z = cvf[2]; f4.w = cvf[3];
            *(float4*)(cp_t + (size_t)(b * DD + d2) * SS + s0) = f4;
            float nvv[4];
#pragma unroll
            for (int r = 0; r < 4; r++) nvv[r] = nv[(size_t)(b * NN + 1 + s0 + r) * DD + d2];
            f4.x = nvv[0]; f4.y = nvv[1]; f4.z = nvv[2]; f4.w = nvv[3];
            *(float4*)(var_t + (size_t)(b * DD + d2) * SS + s0) = f4;
            float vals[24];
#pragma unroll
            for (int r = 0; r < 4; r++) {
                vals[r * 6 + 0] = avf[r]; vals[r * 6 + 1] = avf[r] * avf[r];
                vals[r * 6 + 2] = bvf[r]; vals[r * 6 + 3] = bvf[r] * bvf[r];
                vals[r * 6 + 4] = cvf[r]; vals[r * 6 + 5] = cvf[r] * cvf[r];
            }
            int lane = t & 63, wid = t >> 6;
#pragma unroll
            for (int vv = 0; vv < 24; vv++) {
                float x = vals[vv];
                for (int o = 32; o; o >>= 1) x += __shfl_xor(x, o, 64);
                if (lane == 0) S.part[vv][wid] = x;
            }
        }
        __syncthreads();
        if (t < 24) {
            float ssum = (S.part[t][0] + S.part[t][1]) + (S.part[t][2] + S.part[t][3]);
            int st = t % 6;
            int row = b * SS + s0 + t / 6;
            float m = ssum * (1.f / DD);
            float* dstp = (st == 0) ? ma : (st == 1) ? qa : (st == 2) ? mb
                         : (st == 3) ? qb : (st == 4) ? mc : qc;
            dstp[row] = m;
        }
    } else if (bx < 776) {
        SB& S = sm.b;
        const int idx = bx - 256;
        const int b = idx / 65, n0 = (idx % 65) * 2;
        const int dq = t & 63, kh = t >> 6;
        {
            int r = t >> 8, d2 = t & 255;
            int n = n0 + r; if (n >= NN) n = NN - 1;
            S.rows[r][d2] = nv[(size_t)(b * NN + n) * DD + d2];
        }
        __syncthreads();
        {   // Q,K sweep
            float4 aq[2], ak[2];
#pragma unroll
            for (int r = 0; r < 2; r++) { aq[r] = make_float4(0.f, 0.f, 0.f, 0.f); ak[r] = aq[r]; }
            const int kb = kh * 32;
#pragma unroll 4
            for (int k = kb; k < kb + 32; k++) {
                float4 wq = *(const float4*)&W_q[k * DD + 4 * dq];
                float4 wk = *(const float4*)&W_k[k * DD + 4 * dq];
#pragma unroll
                for (int r = 0; r < 2; r++) {
                    float x = S.rows[r][k];
                    aq[r].x = fmaf(x, wq.x, aq[r].x); aq[r].y = fmaf(x, wq.y, aq[r].y);
                    aq[r].z = fmaf(x, wq.z, aq[r].z); aq[r].w = fmaf(x, wq.w, aq[r].w);
                    ak[r].x = fmaf(x, wk.x, ak[r].x); ak[r].y = fmaf(x, wk.y, ak[r].y);
                    ak[r].z = fmaf(x, wk.z, ak[r].z); ak[r].w = fmaf(x, wk.w, ak[r].w);
                }
            }
#pragma unroll
            for (int r = 0; r < 2; r++) { S.redq[kh][r][dq] = aq[r]; S.redk[kh][r][dq] = ak[r]; }
        }
        __syncthreads();
        {   // finalize q,k -> sq,sk
            const int d2 = t & 255, r = t >> 8;
            const int n = n0 + r;
            float qf = b_q[d2], kf = b_k[d2];
#pragma unroll
            for (int kk = 0; kk < 8; kk++) {
                qf += ((const float*)S.redq[kk][r])[d2];
                kf += ((const float*)S.redk[kk][r])[d2];
            }
            float xq = qf * w_attn[d2 & 31];
            float xk = kf * w_attn[32 + (d2 & 31)];
#pragma unroll
            for (int o = 16; o; o >>= 1) { xq += __shfl_xor(xq, o, 32); xk += __shfl_xor(xk, o, 32); }
            if ((d2 & 31) == 0 && n < NN) {
                sq[(size_t)(b * HH + (d2 >> 5)) * NN + n] = xq;
                sk[(size_t)(b * HH + (d2 >> 5)) * NN + n] = xk;
            }
        }
        __syncthreads();
        {   // V sweep (reuse redq)
            float4 av[2];
#pragma unroll
            for (int r = 0; r < 2; r++) av[r] = make_float4(0.f, 0.f, 0.f, 0.f);
            const int kb = kh * 32;
#pragma unroll 4
            for (int k = kb; k < kb + 32; k++) {
                float4 wv = *(const float4*)&W_v[k * DD + 4 * dq];
#pragma unroll
                for (int r = 0; r < 2; r++) {
                    float x = S.rows[r][k];
                    av[r].x = fmaf(x, wv.x, av[r].x); av[r].y = fmaf(x, wv.y, av[r].y);
                    av[r].z = fmaf(x, wv.z, av[r].z); av[r].w = fmaf(x, wv.w, av[r].w);
                }
            }
#pragma unroll
            for (int r = 0; r < 2; r++) S.redq[kh][r][dq] = av[r];
        }
        __syncthreads();
        {
            const int d2 = t & 255, r = t >> 8;
            const int n = n0 + r;
            if (n < NN) {
                float vf = b_v[d2];
#pragma unroll
                for (int kk = 0; kk < 8; kk++) vf += ((const float*)S.redq[kk][r])[d2];
                v[(size_t)(b * NN + n) * DD + d2] = vf;
            }
        }
    } else {
        const int ri = bx - 776;  // 0..63
        if (t < 256) {
            const int c = t;
            const float wec = w_attn[64 + (c & 31)];
#pragma unroll
            for (int rr = 0; rr < 4; rr++) {
                int r = ri * 4 + rr;
                float x = W_e2[(size_t)r * DD + c] * wec;
#pragma unroll
                for (int o = 16; o; o >>= 1) x += __shfl_xor(x, o, 32);
                if ((c & 31) == 0) U[r * HH + (c >> 5)] = x;
            }
            if (ri == 0) {
                float x = b_e2[c] * wec;
#pragma unroll
                for (int o = 16; o; o >>= 1) x += __shfl_xor(x, o, 32);
                if ((c & 31) == 0) ubias[c >> 5] = x;
            }
        }
    }
}

// ============ KMEGA6: R9 kmega2 + batched loads (deep vmcnt pipelining) =====
// R10/R11/R12 eliminated conflicts/occupancy/LDS-port as the ~50us limiter.
// Remaining model: per-iter load-stall (1-2 loads in flight, ~300cyc each).
// Fix: batch-load 16 (pass2) / 8+8 (pass1) global float2 into registers
// back-to-back, then compute — 16 outstanding vmcnt amortize latency.
__global__ __launch_bounds__(256) void kmega6(
    const float* __restrict__ a, const float* __restrict__ bp_t, const float* __restrict__ cp_t,
    const float* __restrict__ var_t, const float* __restrict__ nv,
    const float* __restrict__ v,
    const float* __restrict__ ma, const float* __restrict__ qa,
    const float* __restrict__ mb, const float* __restrict__ qb,
    const float* __restrict__ mc, const float* __restrict__ qc,
    const float* __restrict__ sq, const float* __restrict__ sk,
    const float* __restrict__ ln_g, const float* __restrict__ ln_b,
    const float* __restrict__ U, const float* __restrict__ ubias,
    const float* __restrict__ b_attn,
    const float* __restrict__ W_o, const float* __restrict__ b_o,
    float* __restrict__ attn, float* __restrict__ out) {
    const int it = blockIdx.x, b = blockIdx.y;
    const int i0 = it * 2;
    const int t = threadIdx.x;
    const int w = t >> 6, l = t & 63;
    const int dgp = l >> 4;            // d-group 0..3 (in-wave -> shuffle-reducible)
    const int jp = w * 16 + (l & 15);  // j-pair 0..63 -> j in {2jp, 2jp+1}

    __shared__ float Arow[2][DD];
    __shared__ __attribute__((aligned(8))) float2 lnsm[DD];
    __shared__ __attribute__((aligned(16))) float4 Usm[DD][2];
    __shared__ __attribute__((aligned(8))) float rsm[2][SS], nmm[2][SS], mkm[2][SS], pnm[2][SS];
    __shared__ float skm[HH * NN];
    __shared__ float sqb[2][HH], ubm[HH];
    __shared__ float sc[2][HH][NN + 3];
    __shared__ union { float Vrow[2][DD]; float csm[2][DD]; } uv;
    __shared__ __attribute__((aligned(16))) union {
        struct { float crs[2][SS]; float dvs[2][SS]; } p1;
        float redc[4][2][DD];
    } ur;

    // ---- stage ----
    {
        int ic0 = i0, ic1 = (i0 + 1 < NN) ? i0 + 1 : NN - 1;
        Arow[0][t] = (ic0 >= 1) ? a[((size_t)b * SS + ic0 - 1) * DD + t] : 0.f;
        Arow[1][t] = (ic1 >= 1) ? a[((size_t)b * SS + ic1 - 1) * DD + t] : 0.f;
        uv.Vrow[0][t] = nv[((size_t)b * NN + ic0) * DD + t];
        uv.Vrow[1][t] = nv[((size_t)b * NN + ic1) * DD + t];
        float2 g; g.x = ln_g[t]; g.y = ln_b[t]; lnsm[t] = g;
        Usm[t][0] = *(const float4*)&U[t * HH];
        Usm[t][1] = *(const float4*)&U[t * HH + 4];
        for (int e = t; e < HH * NN; e += 256) skm[e] = sk[(size_t)b * HH * NN + e];
        if (t < 16) {
            int il = t >> 3, h = t & 7;
            int i = i0 + il; if (i > NN - 1) i = NN - 1;
            sqb[il][h] = sq[(size_t)b * HH * NN + h * NN + i] + b_attn[0];
        }
        if (t < HH) ubm[t] = ubias[t];
    }
    __syncthreads();

    // ---- pass 1: cross = a_{i-1}.bp_j ; dvv = nv_i.var_j (batched 8+8) ----
    {
        float cr[2][2] = {{0.f, 0.f}, {0.f, 0.f}}, dvv[2][2] = {{0.f, 0.f}, {0.f, 0.f}};
        if (i0 != 0 || 1) {  // always run; i0==0 row0 contributes junk ignored by stats
            const float* bc = bp_t + ((size_t)b * DD + dgp * 64) * SS + 2 * jp;
            const float* vc = var_t + ((size_t)b * DD + dgp * 64) * SS + 2 * jp;
            for (int dd0 = 0; dd0 < 64; dd0 += 8) {
                float2 bvv[8], vvv[8];
#pragma unroll
                for (int k2 = 0; k2 < 8; k2++) {
                    bvv[k2] = *(const float2*)(bc + (size_t)(dd0 + k2) * SS);
                    vvv[k2] = *(const float2*)(vc + (size_t)(dd0 + k2) * SS);
                }
#pragma unroll
                for (int k2 = 0; k2 < 8; k2++) {
                    const int d = dgp * 64 + dd0 + k2;
                    float A0 = Arow[0][d], A1 = Arow[1][d];
                    float V0 = uv.Vrow[0][d], V1 = uv.Vrow[1][d];
                    cr[0][0] = fmaf(A0, bvv[k2].x, cr[0][0]); cr[0][1] = fmaf(A0, bvv[k2].y, cr[0][1]);
                    cr[1][0] = fmaf(A1, bvv[k2].x, cr[1][0]); cr[1][1] = fmaf(A1, bvv[k2].y, cr[1][1]);
                    dvv[0][0] = fmaf(V0, vvv[k2].x, dvv[0][0]); dvv[0][1] = fmaf(V0, vvv[k2].y, dvv[0][1]);
                    dvv[1][0] = fmaf(V1, vvv[k2].x, dvv[1][0]); dvv[1][1] = fmaf(V1, vvv[k2].y, dvv[1][1]);
                }
            }
        }
#pragma unroll
        for (int il = 0; il < 2; il++)
#pragma unroll
            for (int jj = 0; jj < 2; jj++) {
                float c = cr[il][jj], d2 = dvv[il][jj];
                c += __shfl_xor(c, 16); c += __shfl_xor(c, 32);
                d2 += __shfl_xor(d2, 16); d2 += __shfl_xor(d2, 32);
                cr[il][jj] = c; dvv[il][jj] = d2;
            }
        if (l < 16) {
#pragma unroll
            for (int il = 0; il < 2; il++) {
                float2 wc; wc.x = cr[il][0]; wc.y = cr[il][1];
                float2 wd; wd.x = dvv[il][0]; wd.y = dvv[il][1];
                *(float2*)&ur.p1.crs[il][2 * jp] = wc;
                *(float2*)&ur.p1.dvs[il][2 * jp] = wd;
            }
        }
    }
    __syncthreads();
    // ---- stats ----
    if (t < SS) {
        const int j = t;
#pragma unroll
        for (int il = 0; il < 2; il++) {
            int i = i0 + il; if (i > NN - 1) i = NN - 1;
            float rs, nm, mk, pen;
            if (i == 0) {
                float mu = mc[b * SS + j], q2 = qc[b * SS + j];
                rs = rsqrtf(q2 - mu * mu + LN_EPS); nm = -mu * rs; mk = 1.f; pen = 0.f;
            } else {
                float cr = ur.p1.crs[il][j];
                float dv = ur.p1.dvs[il][j];
                float muA = ma[b * SS + i - 1], qA = qa[b * SS + i - 1];
                float muB = mb[b * SS + j], qB = qb[b * SS + j];
                float mu = muA + muB;
                float var = qA + qB + 2.f * cr * (1.f / DD) - mu * mu;
                rs = rsqrtf(var + LN_EPS); nm = -mu * rs;
                mk = ((i - 1) != j && dv > 0.f) ? 1.f : 0.f;
                pen = (mk == 0.f) ? -1e9f : 0.f;
            }
            rsm[il][j] = rs; nmm[il][j] = nm; mkm[il][j] = mk; pnm[il][j] = pen;
        }
    }
    __syncthreads();
    // ---- pass 2: LN + relu + U-dot (batched 16; shared B panel) ----
    float acc[2][HH][2];
#pragma unroll
    for (int il = 0; il < 2; il++)
#pragma unroll
        for (int h = 0; h < HH; h++) { acc[il][h][0] = 0.f; acc[il][h][1] = 0.f; }
    {
        const float* Bb = bp_t + ((size_t)b * DD + dgp * 64) * SS + 2 * jp;
        float2 r0 = *(const float2*)&rsm[0][2 * jp];
        float2 n0 = *(const float2*)&nmm[0][2 * jp];
        float2 r1 = *(const float2*)&rsm[1][2 * jp];
        float2 n1 = *(const float2*)&nmm[1][2 * jp];
        if (i0 != 0) {
            for (int dd0 = 0; dd0 < 64; dd0 += 16) {
                float2 bvv[16];
#pragma unroll
                for (int k2 = 0; k2 < 16; k2++)
                    bvv[k2] = *(const float2*)(Bb + (size_t)(dd0 + k2) * SS);
#pragma unroll
                for (int k2 = 0; k2 < 16; k2++) {
                    const int d = dgp * 64 + dd0 + k2;
                    float2 bv = bvv[k2];
                    float A0 = Arow[0][d], A1 = Arow[1][d];
                    float2 gb = lnsm[d];
                    float4 u0 = Usm[d][0], u1 = Usm[d][1];
                    float y0 = fmaf(A0 + bv.x, r0.x, n0.x); y0 = fmaf(y0, gb.x, gb.y);
                    float y1 = fmaf(A0 + bv.y, r0.y, n0.y); y1 = fmaf(y1, gb.x, gb.y);
                    float e0 = fmaxf(y0, 0.f), e1 = fmaxf(y1, 0.f);
                    float z0 = fmaf(A1 + bv.x, r1.x, n1.x); z0 = fmaf(z0, gb.x, gb.y);
                    float z1 = fmaf(A1 + bv.y, r1.y, n1.y); z1 = fmaf(z1, gb.x, gb.y);
                    float f0 = fmaxf(z0, 0.f), f1 = fmaxf(z1, 0.f);
                    acc[0][0][0] = fmaf(e0, u0.x, acc[0][0][0]); acc[0][0][1] = fmaf(e1, u0.x, acc[0][0][1]);
                    acc[0][1][0] = fmaf(e0, u0.y, acc[0][1][0]); acc[0][1][1] = fmaf(e1, u0.y, acc[0][1][1]);
                    acc[0][2][0] = fmaf(e0, u0.z, acc[0][2][0]); acc[0][2][1] = fmaf(e1, u0.z, acc[0][2][1]);
                    acc[0][3][0] = fmaf(e0, u0.w, acc[0][3][0]); acc[0][3][1] = fmaf(e1, u0.w, acc[0][3][1]);
                    acc[0][4][0] = fmaf(e0, u1.x, acc[0][4][0]); acc[0][4][1] = fmaf(e1, u1.x, acc[0][4][1]);
                    acc[0][5][0] = fmaf(e0, u1.y, acc[0][5][0]); acc[0][5][1] = fmaf(e1, u1.y, acc[0][5][1]);
                    acc[0][6][0] = fmaf(e0, u1.z, acc[0][6][0]); acc[0][6][1] = fmaf(e1, u1.z, acc[0][6][1]);
                    acc[0][7][0] = fmaf(e0, u1.w, acc[0][7][0]); acc[0][7][1] = fmaf(e1, u1.w, acc[0][7][1]);
                    acc[1][0][0] = fmaf(f0, u0.x, acc[1][0][0]); acc[1][0][1] = fmaf(f1, u0.x, acc[1][0][1]);
                    acc[1][1][0] = fmaf(f0, u0.y, acc[1][1][0]); acc[1][1][1] = fmaf(f1, u0.y, acc[1][1][1]);
                    acc[1][2][0] = fmaf(f0, u0.z, acc[1][2][0]); acc[1][2][1] = fmaf(f1, u0.z, acc[1][2][1]);
                    acc[1][3][0] = fmaf(f0, u0.w, acc[1][3][0]); acc[1][3][1] = fmaf(f1, u0.w, acc[1][3][1]);
                    acc[1][4][0] = fmaf(f0, u1.x, acc[1][4][0]); acc[1][4][1] = fmaf(f1, u1.x, acc[1][4][1]);
                    acc[1][5][0] = fmaf(f0, u1.y, acc[1][5][0]); acc[1][5][1] = fmaf(f1, u1.y, acc[1][5][1]);
                    acc[1][6][0] = fmaf(f0, u1.z, acc[1][6][0]); acc[1][6][1] = fmaf(f1, u1.z, acc[1][6][1]);
                    acc[1][7][0] = fmaf(f0, u1.w, acc[1][7][0]); acc[1][7][1] = fmaf(f1, u1.w, acc[1][7][1]);
                }
            }
        } else {
            const float* Bc = cp_t + ((size_t)b * DD + dgp * 64) * SS + 2 * jp;
            for (int dd0 = 0; dd0 < 64; dd0 += 8) {
                float2 bAv[8], bBv[8];
#pragma unroll
                for (int k2 = 0; k2 < 8; k2++) {
                    bAv[k2] = *(const float2*)(Bc + (size_t)(dd0 + k2) * SS);
                    bBv[k2] = *(const float2*)(Bb + (size_t)(dd0 + k2) * SS);
                }
#pragma unroll
                for (int k2 = 0; k2 < 8; k2++) {
                    const int d = dgp * 64 + dd0 + k2;
                    float2 bA = bAv[k2], bB = bBv[k2];
                    float A0 = Arow[0][d], A1 = Arow[1][d];
                    float2 gb = lnsm[d];
                    float4 u0 = Usm[d][0], u1 = Usm[d][1];
                    float y0 = fmaf(A0 + bA.x, r0.x, n0.x); y0 = fmaf(y0, gb.x, gb.y);
                    float y1 = fmaf(A0 + bA.y, r0.y, n0.y); y1 = fmaf(y1, gb.x, gb.y);
                    float e0 = fmaxf(y0, 0.f), e1 = fmaxf(y1, 0.f);
                    float z0 = fmaf(A1 + bB.x, r1.x, n1.x); z0 = fmaf(z0, gb.x, gb.y);
                    float z1 = fmaf(A1 + bB.y, r1.y, n1.y); z1 = fmaf(z1, gb.x, gb.y);
                    float f0 = fmaxf(z0, 0.f), f1 = fmaxf(z1, 0.f);
                    acc[0][0][0] = fmaf(e0, u0.x, acc[0][0][0]); acc[0][0][1] = fmaf(e1, u0.x, acc[0][0][1]);
                    acc[0][1][0] = fmaf(e0, u0.y, acc[0][1][0]); acc[0][1][1] = fmaf(e1, u0.y, acc[0][1][1]);
                    acc[0][2][0] = fmaf(e0, u0.z, acc[0][2][0]); acc[0][2][1] = fmaf(e1, u0.z, acc[0][2][1]);
                    acc[0][3][0] = fmaf(e0, u0.w, acc[0][3][0]); acc[0][3][1] = fmaf(e1, u0.w, acc[0][3][1]);
                    acc[0][4][0] = fmaf(e0, u1.x, acc[0][4][0]); acc[0][4][1] = fmaf(e1, u1.x, acc[0][4][1]);
                    acc[0][5][0] = fmaf(e0, u1.y, acc[0][5][0]); acc[0][5][1] = fmaf(e1, u1.y, acc[0][5][1]);
                    acc[0][6][0] = fmaf(e0, u1.z, acc[0][6][0]); acc[0][6][1] = fmaf(e1, u1.z, acc[0][6][1]);
                    acc[0][7][0] = fmaf(e0, u1.w, acc[0][7][0]); acc[0][7][1] = fmaf(e1, u1.w, acc[0][7][1]);
                    acc[1][0][0] = fmaf(f0, u0.x, acc[1][0][0]); acc[1][0][1] = fmaf(f1, u0.x, acc[1][0][1]);
                    acc[1][1][0] = fmaf(f0, u0.y, acc[1][1][0]); acc[1][1][1] = fmaf(f1, u0.y, acc[1][1][1]);
                    acc[1][2][0] = fmaf(f0, u0.z, acc[1][2][0]); acc[1][2][1] = fmaf(f1, u0.z, acc[1][2][1]);
                    acc[1][3][0] = fmaf(f0, u0.w, acc[1][3][0]); acc[1][3][1] = fmaf(f1, u0.w, acc[1][3][1]);
                    acc[1][4][0] = fmaf(f0, u1.x, acc[1][4][0]); acc[1][4][1] = fmaf(f1, u1.x, acc[1][4][1]);
                    acc[1][5][0] = fmaf(f0, u1.y, acc[1][5][0]); acc[1][5][1] = fmaf(f1, u1.y, acc[1][5][1]);
                    acc[1][6][0] = fmaf(f0, u1.z, acc[1][6][0]); acc[1][6][1] = fmaf(f1, u1.z, acc[1][6][1]);
                    acc[1][7][0] = fmaf(f0, u1.w, acc[1][7][0]); acc[1][7][1] = fmaf(f1, u1.w, acc[1][7][1]);
                }
            }
        }
    }
    // in-wave reduce over d-groups, then assemble scores directly
#pragma unroll
    for (int il = 0; il < 2; il++)
#pragma unroll
        for (int h = 0; h < HH; h++) {
            float s0 = acc[il][h][0], s1 = acc[il][h][1];
            s0 += __shfl_xor(s0, 16); s0 += __shfl_xor(s0, 32);
            s1 += __shfl_xor(s1, 16); s1 += __shfl_xor(s1, 32);
            acc[il][h][0] = s0; acc[il][h][1] = s1;
        }
    if (l < 16) {
        const int j0 = 2 * jp, j1 = j0 + 1;
#pragma unroll
        for (int il = 0; il < 2; il++) {
            float mk0 = mkm[il][j0], pn0 = pnm[il][j0];
            float mk1 = mkm[il][j1], pn1 = pnm[il][j1];
#pragma unroll
            for (int h = 0; h < HH; h++) {
                sc[il][h][1 + j0] = sqb[il][h] + skm[h * NN + 1 + j0] + (acc[il][h][0] + ubm[h]) * mk0 + pn0;
                sc[il][h][1 + j1] = sqb[il][h] + skm[h * NN + 1 + j1] + (acc[il][h][1] + ubm[h]) * mk1 + pn1;
            }
        }
    }
    if (t < 16) { int il = t >> 3, h = t & 7; sc[il][h][0] = sqb[il][h] + skm[h * NN] - 1e9f; }
    __syncthreads();
    // ---- softmax: normalize sc in place + write attn ----
    {
        const int row = t >> 4, ll = t & 15;
        const int il = row >> 3, h = row & 7;
        const int i = i0 + il;
        float m = -INFINITY;
        for (int j = ll; j < NN; j += 16) m = fmaxf(m, sc[il][h][j]);
#pragma unroll
        for (int o = 8; o; o >>= 1) m = fmaxf(m, __shfl_xor(m, o, 16));
        float s = 0.f;
        float ev[9];
        int cnt = 0;
        for (int j = ll; j < NN; j += 16) { float e = __expf(sc[il][h][j] - m); ev[cnt++] = e; s += e; }
#pragma unroll
        for (int o = 8; o; o >>= 1) s += __shfl_xor(s, o, 16);
        float inv = 1.f / s;
        float* arow = attn + (((size_t)b * HH + h) * NN + i) * NN;
        cnt = 0;
        for (int j = ll; j < NN; j += 16) {
            float p = ev[cnt++] * inv;
            sc[il][h][j] = p;
            if (i < NN) arow[j] = p;
        }
    }
    __syncthreads();
    // ---- ctx = p @ v (thread = d-quad x j-group; batched 8) ----
    {
        const int dq = t & 63, jg = t >> 6;
        const int h = dq >> 3;
        float ca[2][4] = {{0.f, 0.f, 0.f, 0.f}, {0.f, 0.f, 0.f, 0.f}};
        const int j0 = jg * 33, j1 = (jg == 3) ? NN : j0 + 33;
        for (int jb = j0; jb < j1; jb += 8) {
            float4 vv8[8];
            int nb = (jb + 8 < j1) ? 8 : j1 - jb;
#pragma unroll 8
            for (int k2 = 0; k2 < nb; k2++)
                vv8[k2] = *(const float4*)&v[((size_t)b * NN + jb + k2) * DD + 4 * dq];
#pragma unroll 8
            for (int k2 = 0; k2 < nb; k2++) {
                int j = jb + k2;
                float4 vv = vv8[k2];
                float p0 = sc[0][h][j], p1 = sc[1][h][j];
                ca[0][0] = fmaf(p0, vv.x, ca[0][0]); ca[0][1] = fmaf(p0, vv.y, ca[0][1]);
                ca[0][2] = fmaf(p0, vv.z, ca[0][2]); ca[0][3] = fmaf(p0, vv.w, ca[0][3]);
                ca[1][0] = fmaf(p1, vv.x, ca[1][0]); ca[1][1] = fmaf(p1, vv.y, ca[1][1]);
                ca[1][2] = fmaf(p1, vv.z, ca[1][2]); ca[1][3] = fmaf(p1, vv.w, ca[1][3]);
            }
        }
#pragma unroll
        for (int il = 0; il < 2; il++) {
            float4 wv; wv.x = ca[il][0]; wv.y = ca[il][1]; wv.z = ca[il][2]; wv.w = ca[il][3];
            *(float4*)&ur.redc[jg][il][4 * dq] = wv;
        }
    }
    __syncthreads();
#pragma unroll
    for (int il = 0; il < 2; il++)
        uv.csm[il][t] = (ur.redc[0][il][t] + ur.redc[1][il][t])
                      + (ur.redc[2][il][t] + ur.redc[3][il][t]);
    __syncthreads();
    // ---- out = ctx @ W_o + b_o (thread = c-quad x k-group; batched 8) ----
    {
        const int cq = t & 63, kg = t >> 6;
        float o[2][4] = {{0.f, 0.f, 0.f, 0.f}, {0.f, 0.f, 0.f, 0.f}};
        for (int kb = 0; kb < 64; kb += 8) {
            float4 wv8[8];
#pragma unroll
            for (int k2 = 0; k2 < 8; k2++)
                wv8[k2] = *(const float4*)&W_o[(size_t)(kg * 64 + kb + k2) * DD + 4 * cq];
#pragma unroll
            for (int k2 = 0; k2 < 8; k2++) {
                int k = kg * 64 + kb + k2;
                float4 wv = wv8[k2];
                float c0 = uv.csm[0][k], c1 = uv.csm[1][k];
                o[0][0] = fmaf(c0, wv.x, o[0][0]); o[0][1] = fmaf(c0, wv.y, o[0][1]);
                o[0][2] = fmaf(c0, wv.z, o[0][2]); o[0][3] = fmaf(c0, wv.w, o[0][3]);
                o[1][0] = fmaf(c1, wv.x, o[1][0]); o[1][1] = fmaf(c1, wv.y, o[1][1]);
                o[1][2] = fmaf(c1, wv.z, o[1][2]); o[1][3] = fmaf(c1, wv.w, o[1][3]);
            }
        }
        __syncthreads();  // all csm reads done before redc reuse
#pragma unroll
        for (int il = 0; il < 2; il++) {
            float4 wv; wv.x = o[il][0]; wv.y = o[il][1]; wv.z = o[il][2]; wv.w = o[il][3];
            *(float4*)&ur.redc[kg][il][4 * cq] = wv;
        }
    }
    __syncthreads();
    {
        float bo = b_o[t];
#pragma unroll
        for (int il = 0; il < 2; il++) {
            int i = i0 + il;
            if (i < NN) {
                float s = (ur.redc[0][il][t] + ur.redc[1][il][t])
                        + (ur.redc[2][il][t] + ur.redc[3][il][t]) + bo;
                out[((size_t)b * NN + i) * DD + t] = s;
            }
        }
    }
}

extern "C" void kernel_launch(void* const* d_in, const int* in_sizes, int n_in,
                              void* d_out, int out_size, void* d_ws, size_t ws_size,
                              hipStream_t stream) {
    const float* desc   = (const float*)d_in[0];
    const float* nv     = (const float*)d_in[1];
    const float* W_gt   = (const float*)d_in[2];
    const float* b_gt   = (const float*)d_in[3];
    // d_in[4] topo_bias unused: sigmoid(x)>0 always, so adjacency sign = sample_sim sign
    const float* W_q    = (const float*)d_in[5];
    const float* b_q    = (const float*)d_in[6];
    const float* W_k    = (const float*)d_in[7];
    const float* b_k    = (const float*)d_in[8];
    const float* W_v    = (const float*)d_in[9];
    const float* b_v    = (const float*)d_in[10];
    const float* W_e1   = (const float*)d_in[11];
    const float* b_e1   = (const float*)d_in[12];
    const float* ln_g   = (const float*)d_in[13];
    const float* ln_b   = (const float*)d_in[14];
    const float* W_e2   = (const float*)d_in[15];
    const float* b_e2   = (const float*)d_in[16];
    const float* w_attn = (const float*)d_in[17];
    const float* b_attn = (const float*)d_in[18];
    const float* W_o    = (const float*)d_in[19];
    const float* b_o    = (const float*)d_in[20];

    float* ws   = (float*)d_ws;
    float* a    = ws + OFF_A;
    float* bp_t = ws + OFF_BPT;
    float* cp_t = ws + OFF_CPT;
    float* vart = ws + OFF_VART;
    float* v    = ws + OFF_V;
    float* sq   = ws + OFF_SQ;
    float* sk   = ws + OFF_SK;
    float* ma   = ws + OFF_MA;
    float* qa   = ws + OFF_QA;
    float* mb   = ws + OFF_MB;
    float* qb   = ws + OFF_QB;
    float* mc   = ws + OFF_MC;
    float* qc   = ws + OFF_QC;
    float* U    = ws + OFF_U;
    float* ub   = ws + OFF_UB;

    float* out  = (float*)d_out;
    float* attn = (float*)d_out + (size_t)BB * NN * DD;

    // L1: 256 projA + 520 qkv + 64 U-fold = 840 blocks
    ka_all<<<dim3(840), dim3(512), 0, stream>>>(
        desc, nv, W_gt, b_gt, W_e1, b_e1, W_q, b_q, W_k, b_k, W_v, b_v,
        W_e2, b_e2, w_attn,
        a, bp_t, cp_t, vart, v, sq, sk, ma, qa, mb, qb, mc, qc, U, ub);
    // L2: everything else, one kernel (gram + scores + softmax + ctx + out)
    kmega6<<<dim3(65, BB), dim3(256), 0, stream>>>(
        a, bp_t, cp_t, vart, nv, v, ma, qa, mb, qb, mc, qc, sq, sk,
        ln_g, ln_b, U, ub, b_attn, W_o, b_o, attn, out);
}

// Round 14
// 173.469 us; speedup vs baseline: 1.0694x; 1.0694x over previous
//
#include <hip/hip_runtime.h>
#include <math.h>

#define BB 8
#define SS 128
#define NN 129
#define DD 256
#define HH 8
#define LN_EPS 1e-5f

// ws layout (float offsets)
#define OFF_A    0        // a:     [B][S][D]
#define OFF_BPT  262144   // bp_t:  [B][D][S]  (b_ + b_e1, transposed)
#define OFF_CPT  524288   // cp_t:  [B][D][S]  (a + b_ + b_e1, transposed)
#define OFF_VART 786432   // var_t: [B][D][S]  (nv[:,1:,:] transposed)
#define OFF_V    1048576  // v:     [B][N][D]
#define OFF_SQ   1312768  // sq:    [B][H][N]
#define OFF_SK   1321024  // sk:    [B][H][N]
#define OFF_MA   1329280
#define OFF_QA   1330304
#define OFF_MB   1331328
#define OFF_QB   1332352
#define OFF_MC   1333376
#define OFF_QC   1334400
#define OFF_U    1335424  // U: [D][H]
#define OFF_UB   1337472  // ubias: [H]

struct SA {  // part A: k1 work (~40.4 KB)
    float dsc[4][DD];
    float drow[4][DD];
    float4 red[8][4][64];
    float part[24][4];
};
struct SB {  // part B: k2 work (~34 KB)
    float rows[2][DD];
    float4 redq[8][2][64];
    float4 redk[8][2][64];
};
union SMA { SA a; SB b; };

// ============ KA (R4 structure, empirically fastest): proj + stats + U-fold =
__global__ __launch_bounds__(512) void ka_all(
    const float* __restrict__ desc, const float* __restrict__ nv,
    const float* __restrict__ W_gt, const float* __restrict__ b_gt,
    const float* __restrict__ W_e1, const float* __restrict__ b_e1,
    const float* __restrict__ W_q, const float* __restrict__ b_q,
    const float* __restrict__ W_k, const float* __restrict__ b_k,
    const float* __restrict__ W_v, const float* __restrict__ b_v,
    const float* __restrict__ W_e2, const float* __restrict__ b_e2,
    const float* __restrict__ w_attn,
    float* __restrict__ a, float* __restrict__ bp_t, float* __restrict__ cp_t,
    float* __restrict__ var_t, float* __restrict__ v,
    float* __restrict__ sq, float* __restrict__ sk,
    float* __restrict__ ma, float* __restrict__ qa, float* __restrict__ mb,
    float* __restrict__ qb, float* __restrict__ mc, float* __restrict__ qc,
    float* __restrict__ U, float* __restrict__ ubias) {
    __shared__ SMA sm;
    const int bx = blockIdx.x, t = threadIdx.x;

    if (bx < 256) {
        SA& S = sm.a;
        const int b = bx >> 5, s0 = (bx & 31) * 4;
        const int dq = t & 63, kh = t >> 6;
        for (int e = t; e < 4 * DD; e += 512)
            S.dsc[e >> 8][e & 255] = desc[(size_t)(b * SS + s0 + (e >> 8)) * DD + (e & 255)];
        __syncthreads();
        {   // d-gemm, split-k x8
            float4 acc[4];
#pragma unroll
            for (int r = 0; r < 4; r++) acc[r] = make_float4(0.f, 0.f, 0.f, 0.f);
            const int kb = kh * 32;
#pragma unroll 4
            for (int k = kb; k < kb + 32; k++) {
                float4 w = *(const float4*)&W_gt[k * DD + 4 * dq];
#pragma unroll
                for (int r = 0; r < 4; r++) {
                    float x = S.dsc[r][k];
                    acc[r].x = fmaf(x, w.x, acc[r].x); acc[r].y = fmaf(x, w.y, acc[r].y);
                    acc[r].z = fmaf(x, w.z, acc[r].z); acc[r].w = fmaf(x, w.w, acc[r].w);
                }
            }
#pragma unroll
            for (int r = 0; r < 4; r++) S.red[kh][r][dq] = acc[r];
        }
        __syncthreads();
        for (int e = t; e < 4 * DD; e += 512) {
            int r = e >> 8, d2 = e & 255;
            float s = b_gt[d2];
#pragma unroll
            for (int kk = 0; kk < 8; kk++) s += ((const float*)S.red[kk][r])[d2];
            S.drow[r][d2] = s;
        }
        __syncthreads();
        {   // a-gemm
            float4 acc[4];
#pragma unroll
            for (int r = 0; r < 4; r++) acc[r] = make_float4(0.f, 0.f, 0.f, 0.f);
            const int kb = kh * 32;
#pragma unroll 4
            for (int k = kb; k < kb + 32; k++) {
                float4 w = *(const float4*)&W_e1[k * DD + 4 * dq];
#pragma unroll
                for (int r = 0; r < 4; r++) {
                    float x = S.drow[r][k];
                    acc[r].x = fmaf(x, w.x, acc[r].x); acc[r].y = fmaf(x, w.y, acc[r].y);
                    acc[r].z = fmaf(x, w.z, acc[r].z); acc[r].w = fmaf(x, w.w, acc[r].w);
                }
            }
#pragma unroll
            for (int r = 0; r < 4; r++) S.red[kh][r][dq] = acc[r];
        }
        __syncthreads();
        float avf[4];
        if (t < 256) {
            const int d2 = t;
#pragma unroll
            for (int r = 0; r < 4; r++) {
                float s = 0.f;
#pragma unroll
                for (int kk = 0; kk < 8; kk++) s += ((const float*)S.red[kk][r])[d2];
                avf[r] = s;
                a[(size_t)(b * SS + s0 + r) * DD + d2] = s;
            }
        }
        __syncthreads();
        {   // b-gemm
            float4 acc[4];
#pragma unroll
            for (int r = 0; r < 4; r++) acc[r] = make_float4(0.f, 0.f, 0.f, 0.f);
            const int kb = kh * 32;
#pragma unroll 4
            for (int k = kb; k < kb + 32; k++) {
                float4 w = *(const float4*)&W_e1[(DD + k) * DD + 4 * dq];
#pragma unroll
                for (int r = 0; r < 4; r++) {
                    float x = S.drow[r][k];
                    acc[r].x = fmaf(x, w.x, acc[r].x); acc[r].y = fmaf(x, w.y, acc[r].y);
                    acc[r].z = fmaf(x, w.z, acc[r].z); acc[r].w = fmaf(x, w.w, acc[r].w);
                }
            }
#pragma unroll
            for (int r = 0; r < 4; r++) S.red[kh][r][dq] = acc[r];
        }
        __syncthreads();
        if (t < 256) {
            const int d2 = t;
            float bvf[4], cvf[4];
            float be1 = b_e1[d2];
#pragma unroll
            for (int r = 0; r < 4; r++) {
                float s = 0.f;
#pragma unroll
                for (int kk = 0; kk < 8; kk++) s += ((const float*)S.red[kk][r])[d2];
                bvf[r] = s + be1; cvf[r] = avf[r] + bvf[r];
            }
            float4 f4;
            f4.x = bvf[0]; f4.y = bvf[1]; f4.z = bvf[2]; f4.w = bvf[3];
            *(float4*)(bp_t + (size_t)(b * DD + d2) * SS + s0) = f4;
            f4.x = cvf[0]; f4.y = cvf[1]; f4.z = cvf[2]; f4.w = cvf[3];
            *(float4*)(cp_t + (size_t)(b * DD + d2) * SS + s0) = f4;
            float nvv[4];
#pragma unroll
            for (int r = 0; r < 4; r++) nvv[r] = nv[(size_t)(b * NN + 1 + s0 + r) * DD + d2];
            f4.x = nvv[0]; f4.y = nvv[1]; f4.z = nvv[2]; f4.w = nvv[3];
            *(float4*)(var_t + (size_t)(b * DD + d2) * SS + s0) = f4;
            float vals[24];
#pragma unroll
            for (int r = 0; r < 4; r++) {
                vals[r * 6 + 0] = avf[r]; vals[r * 6 + 1] = avf[r] * avf[r];
                vals[r * 6 + 2] = bvf[r]; vals[r * 6 + 3] = bvf[r] * bvf[r];
                vals[r * 6 + 4] = cvf[r]; vals[r * 6 + 5] = cvf[r] * cvf[r];
            }
            int lane = t & 63, wid = t >> 6;
#pragma unroll
            for (int vv = 0; vv < 24; vv++) {
                float x = vals[vv];
                for (int o = 32; o; o >>= 1) x += __shfl_xor(x, o, 64);
                if (lane == 0) S.part[vv][wid] = x;
            }
        }
        __syncthreads();
        if (t < 24) {
            float ssum = (S.part[t][0] + S.part[t][1]) + (S.part[t][2] + S.part[t][3]);
            int st = t % 6;
            int row = b * SS + s0 + t / 6;
            float m = ssum * (1.f / DD);
            float* dstp = (st == 0) ? ma : (st == 1) ? qa : (st == 2) ? mb
                         : (st == 3) ? qb : (st == 4) ? mc : qc;
            dstp[row] = m;
        }
    } else if (bx < 776) {
        SB& S = sm.b;
        const int idx = bx - 256;
        const int b = idx / 65, n0 = (idx % 65) * 2;
        const int dq = t & 63, kh = t >> 6;
        {
            int r = t >> 8, d2 = t & 255;
            int n = n0 + r; if (n >= NN) n = NN - 1;
            S.rows[r][d2] = nv[(size_t)(b * NN + n) * DD + d2];
        }
        __syncthreads();
        {   // Q,K sweep
            float4 aq[2], ak[2];
#pragma unroll
            for (int r = 0; r < 2; r++) { aq[r] = make_float4(0.f, 0.f, 0.f, 0.f); ak[r] = aq[r]; }
            const int kb = kh * 32;
#pragma unroll 4
            for (int k = kb; k < kb + 32; k++) {
                float4 wq = *(const float4*)&W_q[k * DD + 4 * dq];
                float4 wk = *(const float4*)&W_k[k * DD + 4 * dq];
#pragma unroll
                for (int r = 0; r < 2; r++) {
                    float x = S.rows[r][k];
                    aq[r].x = fmaf(x, wq.x, aq[r].x); aq[r].y = fmaf(x, wq.y, aq[r].y);
                    aq[r].z = fmaf(x, wq.z, aq[r].z); aq[r].w = fmaf(x, wq.w, aq[r].w);
                    ak[r].x = fmaf(x, wk.x, ak[r].x); ak[r].y = fmaf(x, wk.y, ak[r].y);
                    ak[r].z = fmaf(x, wk.z, ak[r].z); ak[r].w = fmaf(x, wk.w, ak[r].w);
                }
            }
#pragma unroll
            for (int r = 0; r < 2; r++) { S.redq[kh][r][dq] = aq[r]; S.redk[kh][r][dq] = ak[r]; }
        }
        __syncthreads();
        {   // finalize q,k -> sq,sk
            const int d2 = t & 255, r = t >> 8;
            const int n = n0 + r;
            float qf = b_q[d2], kf = b_k[d2];
#pragma unroll
            for (int kk = 0; kk < 8; kk++) {
                qf += ((const float*)S.redq[kk][r])[d2];
                kf += ((const float*)S.redk[kk][r])[d2];
            }
            float xq = qf * w_attn[d2 & 31];
            float xk = kf * w_attn[32 + (d2 & 31)];
#pragma unroll
            for (int o = 16; o; o >>= 1) { xq += __shfl_xor(xq, o, 32); xk += __shfl_xor(xk, o, 32); }
            if ((d2 & 31) == 0 && n < NN) {
                sq[(size_t)(b * HH + (d2 >> 5)) * NN + n] = xq;
                sk[(size_t)(b * HH + (d2 >> 5)) * NN + n] = xk;
            }
        }
        __syncthreads();
        {   // V sweep (reuse redq)
            float4 av[2];
#pragma unroll
            for (int r = 0; r < 2; r++) av[r] = make_float4(0.f, 0.f, 0.f, 0.f);
            const int kb = kh * 32;
#pragma unroll 4
            for (int k = kb; k < kb + 32; k++) {
                float4 wv = *(const float4*)&W_v[k * DD + 4 * dq];
#pragma unroll
                for (int r = 0; r < 2; r++) {
                    float x = S.rows[r][k];
                    av[r].x = fmaf(x, wv.x, av[r].x); av[r].y = fmaf(x, wv.y, av[r].y);
                    av[r].z = fmaf(x, wv.z, av[r].z); av[r].w = fmaf(x, wv.w, av[r].w);
                }
            }
#pragma unroll
            for (int r = 0; r < 2; r++) S.redq[kh][r][dq] = av[r];
        }
        __syncthreads();
        {
            const int d2 = t & 255, r = t >> 8;
            const int n = n0 + r;
            if (n < NN) {
                float vf = b_v[d2];
#pragma unroll
                for (int kk = 0; kk < 8; kk++) vf += ((const float*)S.redq[kk][r])[d2];
                v[(size_t)(b * NN + n) * DD + d2] = vf;
            }
        }
    } else {
        const int ri = bx - 776;  // 0..63
        if (t < 256) {
            const int c = t;
            const float wec = w_attn[64 + (c & 31)];
#pragma unroll
            for (int rr = 0; rr < 4; rr++) {
                int r = ri * 4 + rr;
                float x = W_e2[(size_t)r * DD + c] * wec;
#pragma unroll
                for (int o = 16; o; o >>= 1) x += __shfl_xor(x, o, 32);
                if ((c & 31) == 0) U[r * HH + (c >> 5)] = x;
            }
            if (ri == 0) {
                float x = b_e2[c] * wec;
#pragma unroll
                for (int o = 16; o; o >>= 1) x += __shfl_xor(x, o, 32);
                if ((c & 31) == 0) ubias[c >> 5] = x;
            }
        }
    }
}

// ============ KMEGA2 (R9 champion): gram + LN + U-dot + scores + softmax +
// ctx + out. In-wave d-group shuffles, ~38.4 KB LDS, 2-i blocks. ==============
__global__ __launch_bounds__(256) void kmega2(
    const float* __restrict__ a, const float* __restrict__ bp_t, const float* __restrict__ cp_t,
    const float* __restrict__ var_t, const float* __restrict__ nv,
    const float* __restrict__ v,
    const float* __restrict__ ma, const float* __restrict__ qa,
    const float* __restrict__ mb, const float* __restrict__ qb,
    const float* __restrict__ mc, const float* __restrict__ qc,
    const float* __restrict__ sq, const float* __restrict__ sk,
    const float* __restrict__ ln_g, const float* __restrict__ ln_b,
    const float* __restrict__ U, const float* __restrict__ ubias,
    const float* __restrict__ b_attn,
    const float* __restrict__ W_o, const float* __restrict__ b_o,
    float* __restrict__ attn, float* __restrict__ out) {
    const int it = blockIdx.x, b = blockIdx.y;
    const int i0 = it * 2;
    const int t = threadIdx.x;
    const int w = t >> 6, l = t & 63;
    const int dgp = l >> 4;            // d-group 0..3 (in-wave -> shuffle-reducible)
    const int jp = w * 16 + (l & 15);  // j-pair 0..63 -> j in {2jp, 2jp+1}

    __shared__ float Arow[2][DD];
    __shared__ __attribute__((aligned(8))) float2 lnsm[DD];
    __shared__ __attribute__((aligned(16))) float4 Usm[DD][2];
    __shared__ __attribute__((aligned(8))) float rsm[2][SS], nmm[2][SS], mkm[2][SS], pnm[2][SS];
    __shared__ float skm[HH * NN];
    __shared__ float sqb[2][HH], ubm[HH];
    __shared__ float sc[2][HH][NN + 3];
    __shared__ union { float Vrow[2][DD]; float csm[2][DD]; } uv;
    __shared__ __attribute__((aligned(16))) union {
        struct { float crs[2][SS]; float dvs[2][SS]; } p1;
        float redc[4][2][DD];
    } ur;

    // ---- stage ----
    {
        int ic0 = i0, ic1 = (i0 + 1 < NN) ? i0 + 1 : NN - 1;
        Arow[0][t] = (ic0 >= 1) ? a[((size_t)b * SS + ic0 - 1) * DD + t] : 0.f;
        Arow[1][t] = (ic1 >= 1) ? a[((size_t)b * SS + ic1 - 1) * DD + t] : 0.f;
        uv.Vrow[0][t] = nv[((size_t)b * NN + ic0) * DD + t];
        uv.Vrow[1][t] = nv[((size_t)b * NN + ic1) * DD + t];
        float2 g; g.x = ln_g[t]; g.y = ln_b[t]; lnsm[t] = g;
        Usm[t][0] = *(const float4*)&U[t * HH];
        Usm[t][1] = *(const float4*)&U[t * HH + 4];
        for (int e = t; e < HH * NN; e += 256) skm[e] = sk[(size_t)b * HH * NN + e];
        if (t < 16) {
            int il = t >> 3, h = t & 7;
            int i = i0 + il; if (i > NN - 1) i = NN - 1;
            sqb[il][h] = sq[(size_t)b * HH * NN + h * NN + i] + b_attn[0];
        }
        if (t < HH) ubm[t] = ubias[t];
    }
    __syncthreads();

    // ---- pass 1: cross = a_{i-1}.bp_j ; dvv = nv_i.var_j (shuffle-reduced) --
    {
        float cr[2][2] = {{0.f, 0.f}, {0.f, 0.f}}, dvv[2][2] = {{0.f, 0.f}, {0.f, 0.f}};
        const float* bc = bp_t + ((size_t)b * DD + dgp * 64) * SS + 2 * jp;
        const float* vc = var_t + ((size_t)b * DD + dgp * 64) * SS + 2 * jp;
#pragma unroll 4
        for (int dd = 0; dd < 64; dd++) {
            float2 bv = *(const float2*)(bc + (size_t)dd * SS);
            float2 vv = *(const float2*)(vc + (size_t)dd * SS);
            const int d = dgp * 64 + dd;
            float A0 = Arow[0][d], A1 = Arow[1][d];
            float V0 = uv.Vrow[0][d], V1 = uv.Vrow[1][d];
            cr[0][0] = fmaf(A0, bv.x, cr[0][0]); cr[0][1] = fmaf(A0, bv.y, cr[0][1]);
            cr[1][0] = fmaf(A1, bv.x, cr[1][0]); cr[1][1] = fmaf(A1, bv.y, cr[1][1]);
            dvv[0][0] = fmaf(V0, vv.x, dvv[0][0]); dvv[0][1] = fmaf(V0, vv.y, dvv[0][1]);
            dvv[1][0] = fmaf(V1, vv.x, dvv[1][0]); dvv[1][1] = fmaf(V1, vv.y, dvv[1][1]);
        }
#pragma unroll
        for (int il = 0; il < 2; il++)
#pragma unroll
            for (int jj = 0; jj < 2; jj++) {
                float c = cr[il][jj], d2 = dvv[il][jj];
                c += __shfl_xor(c, 16); c += __shfl_xor(c, 32);
                d2 += __shfl_xor(d2, 16); d2 += __shfl_xor(d2, 32);
                cr[il][jj] = c; dvv[il][jj] = d2;
            }
        if (l < 16) {
#pragma unroll
            for (int il = 0; il < 2; il++) {
                float2 wc; wc.x = cr[il][0]; wc.y = cr[il][1];
                float2 wd; wd.x = dvv[il][0]; wd.y = dvv[il][1];
                *(float2*)&ur.p1.crs[il][2 * jp] = wc;
                *(float2*)&ur.p1.dvs[il][2 * jp] = wd;
            }
        }
    }
    __syncthreads();
    // ---- stats ----
    if (t < SS) {
        const int j = t;
#pragma unroll
        for (int il = 0; il < 2; il++) {
            int i = i0 + il; if (i > NN - 1) i = NN - 1;
            float rs, nm, mk, pen;
            if (i == 0) {
                float mu = mc[b * SS + j], q2 = qc[b * SS + j];
                rs = rsqrtf(q2 - mu * mu + LN_EPS); nm = -mu * rs; mk = 1.f; pen = 0.f;
            } else {
                float cr = ur.p1.crs[il][j];
                float dv = ur.p1.dvs[il][j];
                float muA = ma[b * SS + i - 1], qA = qa[b * SS + i - 1];
                float muB = mb[b * SS + j], qB = qb[b * SS + j];
                float mu = muA + muB;
                float var = qA + qB + 2.f * cr * (1.f / DD) - mu * mu;
                rs = rsqrtf(var + LN_EPS); nm = -mu * rs;
                mk = ((i - 1) != j && dv > 0.f) ? 1.f : 0.f;
                pen = (mk == 0.f) ? -1e9f : 0.f;
            }
            rsm[il][j] = rs; nmm[il][j] = nm; mkm[il][j] = mk; pnm[il][j] = pen;
        }
    }
    __syncthreads();
    // ---- pass 2: LN + relu + U-dot (shared B panel; shuffle-reduced) ----
    float acc[2][HH][2];
#pragma unroll
    for (int il = 0; il < 2; il++)
#pragma unroll
        for (int h = 0; h < HH; h++) { acc[il][h][0] = 0.f; acc[il][h][1] = 0.f; }
    {
        const float* Bb = bp_t + ((size_t)b * DD + dgp * 64) * SS + 2 * jp;
        float2 r0 = *(const float2*)&rsm[0][2 * jp];
        float2 n0 = *(const float2*)&nmm[0][2 * jp];
        float2 r1 = *(const float2*)&rsm[1][2 * jp];
        float2 n1 = *(const float2*)&nmm[1][2 * jp];
        if (i0 != 0) {
#pragma unroll 4
            for (int dd = 0; dd < 64; dd++) {
                const int d = dgp * 64 + dd;
                float2 bv = *(const float2*)(Bb + (size_t)dd * SS);
                float A0 = Arow[0][d], A1 = Arow[1][d];
                float2 gb = lnsm[d];
                float4 u0 = Usm[d][0], u1 = Usm[d][1];
                float y0 = fmaf(A0 + bv.x, r0.x, n0.x); y0 = fmaf(y0, gb.x, gb.y);
                float y1 = fmaf(A0 + bv.y, r0.y, n0.y); y1 = fmaf(y1, gb.x, gb.y);
                float e0 = fmaxf(y0, 0.f), e1 = fmaxf(y1, 0.f);
                float z0 = fmaf(A1 + bv.x, r1.x, n1.x); z0 = fmaf(z0, gb.x, gb.y);
                float z1 = fmaf(A1 + bv.y, r1.y, n1.y); z1 = fmaf(z1, gb.x, gb.y);
                float f0 = fmaxf(z0, 0.f), f1 = fmaxf(z1, 0.f);
                acc[0][0][0] = fmaf(e0, u0.x, acc[0][0][0]); acc[0][0][1] = fmaf(e1, u0.x, acc[0][0][1]);
                acc[0][1][0] = fmaf(e0, u0.y, acc[0][1][0]); acc[0][1][1] = fmaf(e1, u0.y, acc[0][1][1]);
                acc[0][2][0] = fmaf(e0, u0.z, acc[0][2][0]); acc[0][2][1] = fmaf(e1, u0.z, acc[0][2][1]);
                acc[0][3][0] = fmaf(e0, u0.w, acc[0][3][0]); acc[0][3][1] = fmaf(e1, u0.w, acc[0][3][1]);
                acc[0][4][0] = fmaf(e0, u1.x, acc[0][4][0]); acc[0][4][1] = fmaf(e1, u1.x, acc[0][4][1]);
                acc[0][5][0] = fmaf(e0, u1.y, acc[0][5][0]); acc[0][5][1] = fmaf(e1, u1.y, acc[0][5][1]);
                acc[0][6][0] = fmaf(e0, u1.z, acc[0][6][0]); acc[0][6][1] = fmaf(e1, u1.z, acc[0][6][1]);
                acc[0][7][0] = fmaf(e0, u1.w, acc[0][7][0]); acc[0][7][1] = fmaf(e1, u1.w, acc[0][7][1]);
                acc[1][0][0] = fmaf(f0, u0.x, acc[1][0][0]); acc[1][0][1] = fmaf(f1, u0.x, acc[1][0][1]);
                acc[1][1][0] = fmaf(f0, u0.y, acc[1][1][0]); acc[1][1][1] = fmaf(f1, u0.y, acc[1][1][1]);
                acc[1][2][0] = fmaf(f0, u0.z, acc[1][2][0]); acc[1][2][1] = fmaf(f1, u0.z, acc[1][2][1]);
                acc[1][3][0] = fmaf(f0, u0.w, acc[1][3][0]); acc[1][3][1] = fmaf(f1, u0.w, acc[1][3][1]);
                acc[1][4][0] = fmaf(f0, u1.x, acc[1][4][0]); acc[1][4][1] = fmaf(f1, u1.x, acc[1][4][1]);
                acc[1][5][0] = fmaf(f0, u1.y, acc[1][5][0]); acc[1][5][1] = fmaf(f1, u1.y, acc[1][5][1]);
                acc[1][6][0] = fmaf(f0, u1.z, acc[1][6][0]); acc[1][6][1] = fmaf(f1, u1.z, acc[1][6][1]);
                acc[1][7][0] = fmaf(f0, u1.w, acc[1][7][0]); acc[1][7][1] = fmaf(f1, u1.w, acc[1][7][1]);
            }
        } else {
            const float* Bc = cp_t + ((size_t)b * DD + dgp * 64) * SS + 2 * jp;
#pragma unroll 4
            for (int dd = 0; dd < 64; dd++) {
                const int d = dgp * 64 + dd;
                float2 bA = *(const float2*)(Bc + (size_t)dd * SS);
                float2 bB = *(const float2*)(Bb + (size_t)dd * SS);
                float A0 = Arow[0][d], A1 = Arow[1][d];
                float2 gb = lnsm[d];
                float4 u0 = Usm[d][0], u1 = Usm[d][1];
                float y0 = fmaf(A0 + bA.x, r0.x, n0.x); y0 = fmaf(y0, gb.x, gb.y);
                float y1 = fmaf(A0 + bA.y, r0.y, n0.y); y1 = fmaf(y1, gb.x, gb.y);
                float e0 = fmaxf(y0, 0.f), e1 = fmaxf(y1, 0.f);
                float z0 = fmaf(A1 + bB.x, r1.x, n1.x); z0 = fmaf(z0, gb.x, gb.y);
                float z1 = fmaf(A1 + bB.y, r1.y, n1.y); z1 = fmaf(z1, gb.x, gb.y);
                float f0 = fmaxf(z0, 0.f), f1 = fmaxf(z1, 0.f);
                acc[0][0][0] = fmaf(e0, u0.x, acc[0][0][0]); acc[0][0][1] = fmaf(e1, u0.x, acc[0][0][1]);
                acc[0][1][0] = fmaf(e0, u0.y, acc[0][1][0]); acc[0][1][1] = fmaf(e1, u0.y, acc[0][1][1]);
                acc[0][2][0] = fmaf(e0, u0.z, acc[0][2][0]); acc[0][2][1] = fmaf(e1, u0.z, acc[0][2][1]);
                acc[0][3][0] = fmaf(e0, u0.w, acc[0][3][0]); acc[0][3][1] = fmaf(e1, u0.w, acc[0][3][1]);
                acc[0][4][0] = fmaf(e0, u1.x, acc[0][4][0]); acc[0][4][1] = fmaf(e1, u1.x, acc[0][4][1]);
                acc[0][5][0] = fmaf(e0, u1.y, acc[0][5][0]); acc[0][5][1] = fmaf(e1, u1.y, acc[0][5][1]);
                acc[0][6][0] = fmaf(e0, u1.z, acc[0][6][0]); acc[0][6][1] = fmaf(e1, u1.z, acc[0][6][1]);
                acc[0][7][0] = fmaf(e0, u1.w, acc[0][7][0]); acc[0][7][1] = fmaf(e1, u1.w, acc[0][7][1]);
                acc[1][0][0] = fmaf(f0, u0.x, acc[1][0][0]); acc[1][0][1] = fmaf(f1, u0.x, acc[1][0][1]);
                acc[1][1][0] = fmaf(f0, u0.y, acc[1][1][0]); acc[1][1][1] = fmaf(f1, u0.y, acc[1][1][1]);
                acc[1][2][0] = fmaf(f0, u0.z, acc[1][2][0]); acc[1][2][1] = fmaf(f1, u0.z, acc[1][2][1]);
                acc[1][3][0] = fmaf(f0, u0.w, acc[1][3][0]); acc[1][3][1] = fmaf(f1, u0.w, acc[1][3][1]);
                acc[1][4][0] = fmaf(f0, u1.x, acc[1][4][0]); acc[1][4][1] = fmaf(f1, u1.x, acc[1][4][1]);
                acc[1][5][0] = fmaf(f0, u1.y, acc[1][5][0]); acc[1][5][1] = fmaf(f1, u1.y, acc[1][5][1]);
                acc[1][6][0] = fmaf(f0, u1.z, acc[1][6][0]); acc[1][6][1] = fmaf(f1, u1.z, acc[1][6][1]);
                acc[1][7][0] = fmaf(f0, u1.w, acc[1][7][0]); acc[1][7][1] = fmaf(f1, u1.w, acc[1][7][1]);
            }
        }
    }
    // in-wave reduce over d-groups, then assemble scores directly
#pragma unroll
    for (int il = 0; il < 2; il++)
#pragma unroll
        for (int h = 0; h < HH; h++) {
            float s0 = acc[il][h][0], s1 = acc[il][h][1];
            s0 += __shfl_xor(s0, 16); s0 += __shfl_xor(s0, 32);
            s1 += __shfl_xor(s1, 16); s1 += __shfl_xor(s1, 32);
            acc[il][h][0] = s0; acc[il][h][1] = s1;
        }
    if (l < 16) {
        const int j0 = 2 * jp, j1 = j0 + 1;
#pragma unroll
        for (int il = 0; il < 2; il++) {
            float mk0 = mkm[il][j0], pn0 = pnm[il][j0];
            float mk1 = mkm[il][j1], pn1 = pnm[il][j1];
#pragma unroll
            for (int h = 0; h < HH; h++) {
                sc[il][h][1 + j0] = sqb[il][h] + skm[h * NN + 1 + j0] + (acc[il][h][0] + ubm[h]) * mk0 + pn0;
                sc[il][h][1 + j1] = sqb[il][h] + skm[h * NN + 1 + j1] + (acc[il][h][1] + ubm[h]) * mk1 + pn1;
            }
        }
    }
    if (t < 16) { int il = t >> 3, h = t & 7; sc[il][h][0] = sqb[il][h] + skm[h * NN] - 1e9f; }
    __syncthreads();
    // ---- softmax: normalize sc in place + write attn ----
    {
        const int row = t >> 4, ll = t & 15;
        const int il = row >> 3, h = row & 7;
        const int i = i0 + il;
        float m = -INFINITY;
        for (int j = ll; j < NN; j += 16) m = fmaxf(m, sc[il][h][j]);
#pragma unroll
        for (int o = 8; o; o >>= 1) m = fmaxf(m, __shfl_xor(m, o, 16));
        float s = 0.f;
        float ev[9];
        int cnt = 0;
        for (int j = ll; j < NN; j += 16) { float e = __expf(sc[il][h][j] - m); ev[cnt++] = e; s += e; }
#pragma unroll
        for (int o = 8; o; o >>= 1) s += __shfl_xor(s, o, 16);
        float inv = 1.f / s;
        float* arow = attn + (((size_t)b * HH + h) * NN + i) * NN;
        cnt = 0;
        for (int j = ll; j < NN; j += 16) {
            float p = ev[cnt++] * inv;
            sc[il][h][j] = p;
            if (i < NN) arow[j] = p;
        }
    }
    __syncthreads();
    // ---- ctx = p @ v (thread = d-quad x j-group) ----
    {
        const int dq = t & 63, jg = t >> 6;
        const int h = dq >> 3;
        float ca[2][4] = {{0.f, 0.f, 0.f, 0.f}, {0.f, 0.f, 0.f, 0.f}};
#pragma unroll 4
        for (int jj = 0; jj < 33; jj++) {
            int j = jg * 33 + jj;
            if (j < NN) {
                float4 vv = *(const float4*)&v[((size_t)b * NN + j) * DD + 4 * dq];
                float p0 = sc[0][h][j], p1 = sc[1][h][j];
                ca[0][0] = fmaf(p0, vv.x, ca[0][0]); ca[0][1] = fmaf(p0, vv.y, ca[0][1]);
                ca[0][2] = fmaf(p0, vv.z, ca[0][2]); ca[0][3] = fmaf(p0, vv.w, ca[0][3]);
                ca[1][0] = fmaf(p1, vv.x, ca[1][0]); ca[1][1] = fmaf(p1, vv.y, ca[1][1]);
                ca[1][2] = fmaf(p1, vv.z, ca[1][2]); ca[1][3] = fmaf(p1, vv.w, ca[1][3]);
            }
        }
#pragma unroll
        for (int il = 0; il < 2; il++) {
            float4 wv; wv.x = ca[il][0]; wv.y = ca[il][1]; wv.z = ca[il][2]; wv.w = ca[il][3];
            *(float4*)&ur.redc[jg][il][4 * dq] = wv;
        }
    }
    __syncthreads();
#pragma unroll
    for (int il = 0; il < 2; il++)
        uv.csm[il][t] = (ur.redc[0][il][t] + ur.redc[1][il][t])
                      + (ur.redc[2][il][t] + ur.redc[3][il][t]);
    __syncthreads();
    // ---- out = ctx @ W_o + b_o (thread = c-quad x k-group) ----
    {
        const int cq = t & 63, kg = t >> 6;
        float o[2][4] = {{0.f, 0.f, 0.f, 0.f}, {0.f, 0.f, 0.f, 0.f}};
#pragma unroll 4
        for (int kk = 0; kk < 64; kk++) {
            int k = kg * 64 + kk;
            float4 wv = *(const float4*)&W_o[(size_t)k * DD + 4 * cq];
            float c0 = uv.csm[0][k], c1 = uv.csm[1][k];
            o[0][0] = fmaf(c0, wv.x, o[0][0]); o[0][1] = fmaf(c0, wv.y, o[0][1]);
            o[0][2] = fmaf(c0, wv.z, o[0][2]); o[0][3] = fmaf(c0, wv.w, o[0][3]);
            o[1][0] = fmaf(c1, wv.x, o[1][0]); o[1][1] = fmaf(c1, wv.y, o[1][1]);
            o[1][2] = fmaf(c1, wv.z, o[1][2]); o[1][3] = fmaf(c1, wv.w, o[1][3]);
        }
        __syncthreads();  // all csm reads done before redc reuse
#pragma unroll
        for (int il = 0; il < 2; il++) {
            float4 wv; wv.x = o[il][0]; wv.y = o[il][1]; wv.z = o[il][2]; wv.w = o[il][3];
            *(float4*)&ur.redc[kg][il][4 * cq] = wv;
        }
    }
    __syncthreads();
    {
        float bo = b_o[t];
#pragma unroll
        for (int il = 0; il < 2; il++) {
            int i = i0 + il;
            if (i < NN) {
                float s = (ur.redc[0][il][t] + ur.redc[1][il][t])
                        + (ur.redc[2][il][t] + ur.redc[3][il][t]) + bo;
                out[((size_t)b * NN + i) * DD + t] = s;
            }
        }
    }
}

extern "C" void kernel_launch(void* const* d_in, const int* in_sizes, int n_in,
                              void* d_out, int out_size, void* d_ws, size_t ws_size,
                              hipStream_t stream) {
    const float* desc   = (const float*)d_in[0];
    const float* nv     = (const float*)d_in[1];
    const float* W_gt   = (const float*)d_in[2];
    const float* b_gt   = (const float*)d_in[3];
    // d_in[4] topo_bias unused: sigmoid(x)>0 always, so adjacency sign = sample_sim sign
    const float* W_q    = (const float*)d_in[5];
    const float* b_q    = (const float*)d_in[6];
    const float* W_k    = (const float*)d_in[7];
    const float* b_k    = (const float*)d_in[8];
    const float* W_v    = (const float*)d_in[9];
    const float* b_v    = (const float*)d_in[10];
    const float* W_e1   = (const float*)d_in[11];
    const float* b_e1   = (const float*)d_in[12];
    const float* ln_g   = (const float*)d_in[13];
    const float* ln_b   = (const float*)d_in[14];
    const float* W_e2   = (const float*)d_in[15];
    const float* b_e2   = (const float*)d_in[16];
    const float* w_attn = (const float*)d_in[17];
    const float* b_attn = (const float*)d_in[18];
    const float* W_o    = (const float*)d_in[19];
    const float* b_o    = (const float*)d_in[20];

    float* ws   = (float*)d_ws;
    float* a    = ws + OFF_A;
    float* bp_t = ws + OFF_BPT;
    float* cp_t = ws + OFF_CPT;
    float* vart = ws + OFF_VART;
    float* v    = ws + OFF_V;
    float* sq   = ws + OFF_SQ;
    float* sk   = ws + OFF_SK;
    float* ma   = ws + OFF_MA;
    float* qa   = ws + OFF_QA;
    float* mb   = ws + OFF_MB;
    float* qb   = ws + OFF_QB;
    float* mc   = ws + OFF_MC;
    float* qc   = ws + OFF_QC;
    float* U    = ws + OFF_U;
    float* ub   = ws + OFF_UB;

    float* out  = (float*)d_out;
    float* attn = (float*)d_out + (size_t)BB * NN * DD;

    // L1: 256 projA + 520 qkv + 64 U-fold = 840 blocks
    ka_all<<<dim3(840), dim3(512), 0, stream>>>(
        desc, nv, W_gt, b_gt, W_e1, b_e1, W_q, b_q, W_k, b_k, W_v, b_v,
        W_e2, b_e2, w_attn,
        a, bp_t, cp_t, vart, v, sq, sk, ma, qa, mb, qb, mc, qc, U, ub);
    // L2: everything else, one kernel (gram + scores + softmax + ctx + out)
    kmega2<<<dim3(65, BB), dim3(256), 0, stream>>>(
        a, bp_t, cp_t, vart, nv, v, ma, qa, mb, qb, mc, qc, sq, sk,
        ln_g, ln_b, U, ub, b_attn, W_o, b_o, attn, out);
}

// Round 15
// 172.612 us; speedup vs baseline: 1.0747x; 1.0050x over previous
//
#include <hip/hip_runtime.h>
#include <math.h>

#define BB 8
#define SS 128
#define NN 129
#define DD 256
#define HH 8
#define LN_EPS 1e-5f

// ws layout (float offsets)
#define OFF_A    0        // a:     [B][S][D]
#define OFF_BPT  262144   // bp_t:  [B][D][S]  (b_ + b_e1, transposed)
#define OFF_CPT  524288   // cp_t:  [B][D][S]  (a + b_ + b_e1, transposed)
#define OFF_VART 786432   // var_t: [B][D][S]  (nv[:,1:,:] transposed)
#define OFF_V    1048576  // v:     [B][N][D]
#define OFF_SQ   1312768  // sq:    [B][H][N]
#define OFF_SK   1321024  // sk:    [B][H][N]
#define OFF_MA   1329280
#define OFF_QA   1330304
#define OFF_MB   1331328
#define OFF_QB   1332352
#define OFF_MC   1333376
#define OFF_QC   1334400
#define OFF_U    1335424  // U: [D][H]
#define OFF_UB   1337472  // ubias: [H]

struct SA {  // part A: k1 work (~40.4 KB)
    float dsc[4][DD];
    float drow[4][DD];
    float4 red[8][4][64];
    float part[24][4];
};
struct SB {  // part B: k2 work (~34 KB)
    float rows[2][DD];
    float4 redq[8][2][64];
    float4 redk[8][2][64];
};
union SMA { SA a; SB b; };

// ============ KA (R4 structure, empirically fastest): proj + stats + U-fold =
__global__ __launch_bounds__(512) void ka_all(
    const float* __restrict__ desc, const float* __restrict__ nv,
    const float* __restrict__ W_gt, const float* __restrict__ b_gt,
    const float* __restrict__ W_e1, const float* __restrict__ b_e1,
    const float* __restrict__ W_q, const float* __restrict__ b_q,
    const float* __restrict__ W_k, const float* __restrict__ b_k,
    const float* __restrict__ W_v, const float* __restrict__ b_v,
    const float* __restrict__ W_e2, const float* __restrict__ b_e2,
    const float* __restrict__ w_attn,
    float* __restrict__ a, float* __restrict__ bp_t, float* __restrict__ cp_t,
    float* __restrict__ var_t, float* __restrict__ v,
    float* __restrict__ sq, float* __restrict__ sk,
    float* __restrict__ ma, float* __restrict__ qa, float* __restrict__ mb,
    float* __restrict__ qb, float* __restrict__ mc, float* __restrict__ qc,
    float* __restrict__ U, float* __restrict__ ubias) {
    __shared__ SMA sm;
    const int bx = blockIdx.x, t = threadIdx.x;

    if (bx < 256) {
        SA& S = sm.a;
        const int b = bx >> 5, s0 = (bx & 31) * 4;
        const int dq = t & 63, kh = t >> 6;
        for (int e = t; e < 4 * DD; e += 512)
            S.dsc[e >> 8][e & 255] = desc[(size_t)(b * SS + s0 + (e >> 8)) * DD + (e & 255)];
        __syncthreads();
        {   // d-gemm, split-k x8
            float4 acc[4];
#pragma unroll
            for (int r = 0; r < 4; r++) acc[r] = make_float4(0.f, 0.f, 0.f, 0.f);
            const int kb = kh * 32;
#pragma unroll 4
            for (int k = kb; k < kb + 32; k++) {
                float4 w = *(const float4*)&W_gt[k * DD + 4 * dq];
#pragma unroll
                for (int r = 0; r < 4; r++) {
                    float x = S.dsc[r][k];
                    acc[r].x = fmaf(x, w.x, acc[r].x); acc[r].y = fmaf(x, w.y, acc[r].y);
                    acc[r].z = fmaf(x, w.z, acc[r].z); acc[r].w = fmaf(x, w.w, acc[r].w);
                }
            }
#pragma unroll
            for (int r = 0; r < 4; r++) S.red[kh][r][dq] = acc[r];
        }
        __syncthreads();
        for (int e = t; e < 4 * DD; e += 512) {
            int r = e >> 8, d2 = e & 255;
            float s = b_gt[d2];
#pragma unroll
            for (int kk = 0; kk < 8; kk++) s += ((const float*)S.red[kk][r])[d2];
            S.drow[r][d2] = s;
        }
        __syncthreads();
        {   // a-gemm
            float4 acc[4];
#pragma unroll
            for (int r = 0; r < 4; r++) acc[r] = make_float4(0.f, 0.f, 0.f, 0.f);
            const int kb = kh * 32;
#pragma unroll 4
            for (int k = kb; k < kb + 32; k++) {
                float4 w = *(const float4*)&W_e1[k * DD + 4 * dq];
#pragma unroll
                for (int r = 0; r < 4; r++) {
                    float x = S.drow[r][k];
                    acc[r].x = fmaf(x, w.x, acc[r].x); acc[r].y = fmaf(x, w.y, acc[r].y);
                    acc[r].z = fmaf(x, w.z, acc[r].z); acc[r].w = fmaf(x, w.w, acc[r].w);
                }
            }
#pragma unroll
            for (int r = 0; r < 4; r++) S.red[kh][r][dq] = acc[r];
        }
        __syncthreads();
        float avf[4];
        if (t < 256) {
            const int d2 = t;
#pragma unroll
            for (int r = 0; r < 4; r++) {
                float s = 0.f;
#pragma unroll
                for (int kk = 0; kk < 8; kk++) s += ((const float*)S.red[kk][r])[d2];
                avf[r] = s;
                a[(size_t)(b * SS + s0 + r) * DD + d2] = s;
            }
        }
        __syncthreads();
        {   // b-gemm
            float4 acc[4];
#pragma unroll
            for (int r = 0; r < 4; r++) acc[r] = make_float4(0.f, 0.f, 0.f, 0.f);
            const int kb = kh * 32;
#pragma unroll 4
            for (int k = kb; k < kb + 32; k++) {
                float4 w = *(const float4*)&W_e1[(DD + k) * DD + 4 * dq];
#pragma unroll
                for (int r = 0; r < 4; r++) {
                    float x = S.drow[r][k];
                    acc[r].x = fmaf(x, w.x, acc[r].x); acc[r].y = fmaf(x, w.y, acc[r].y);
                    acc[r].z = fmaf(x, w.z, acc[r].z); acc[r].w = fmaf(x, w.w, acc[r].w);
                }
            }
#pragma unroll
            for (int r = 0; r < 4; r++) S.red[kh][r][dq] = acc[r];
        }
        __syncthreads();
        if (t < 256) {
            const int d2 = t;
            float bvf[4], cvf[4];
            float be1 = b_e1[d2];
#pragma unroll
            for (int r = 0; r < 4; r++) {
                float s = 0.f;
#pragma unroll
                for (int kk = 0; kk < 8; kk++) s += ((const float*)S.red[kk][r])[d2];
                bvf[r] = s + be1; cvf[r] = avf[r] + bvf[r];
            }
            float4 f4;
            f4.x = bvf[0]; f4.y = bvf[1]; f4.z = bvf[2]; f4.w = bvf[3];
            *(float4*)(bp_t + (size_t)(b * DD + d2) * SS + s0) = f4;
            f4.x = cvf[0]; f4.y = cvf[1]; f4.z = cvf[2]; f4.w = cvf[3];
            *(float4*)(cp_t + (size_t)(b * DD + d2) * SS + s0) = f4;
            float nvv[4];
#pragma unroll
            for (int r = 0; r < 4; r++) nvv[r] = nv[(size_t)(b * NN + 1 + s0 + r) * DD + d2];
            f4.x = nvv[0]; f4.y = nvv[1]; f4.z = nvv[2]; f4.w = nvv[3];
            *(float4*)(var_t + (size_t)(b * DD + d2) * SS + s0) = f4;
            float vals[24];
#pragma unroll
            for (int r = 0; r < 4; r++) {
                vals[r * 6 + 0] = avf[r]; vals[r * 6 + 1] = avf[r] * avf[r];
                vals[r * 6 + 2] = bvf[r]; vals[r * 6 + 3] = bvf[r] * bvf[r];
                vals[r * 6 + 4] = cvf[r]; vals[r * 6 + 5] = cvf[r] * cvf[r];
            }
            int lane = t & 63, wid = t >> 6;
#pragma unroll
            for (int vv = 0; vv < 24; vv++) {
                float x = vals[vv];
                for (int o = 32; o; o >>= 1) x += __shfl_xor(x, o, 64);
                if (lane == 0) S.part[vv][wid] = x;
            }
        }
        __syncthreads();
        if (t < 24) {
            float ssum = (S.part[t][0] + S.part[t][1]) + (S.part[t][2] + S.part[t][3]);
            int st = t % 6;
            int row = b * SS + s0 + t / 6;
            float m = ssum * (1.f / DD);
            float* dstp = (st == 0) ? ma : (st == 1) ? qa : (st == 2) ? mb
                         : (st == 3) ? qb : (st == 4) ? mc : qc;
            dstp[row] = m;
        }
    } else if (bx < 776) {
        SB& S = sm.b;
        const int idx = bx - 256;
        const int b = idx / 65, n0 = (idx % 65) * 2;
        const int dq = t & 63, kh = t >> 6;
        {
            int r = t >> 8, d2 = t & 255;
            int n = n0 + r; if (n >= NN) n = NN - 1;
            S.rows[r][d2] = nv[(size_t)(b * NN + n) * DD + d2];
        }
        __syncthreads();
        {   // Q,K sweep
            float4 aq[2], ak[2];
#pragma unroll
            for (int r = 0; r < 2; r++) { aq[r] = make_float4(0.f, 0.f, 0.f, 0.f); ak[r] = aq[r]; }
            const int kb = kh * 32;
#pragma unroll 4
            for (int k = kb; k < kb + 32; k++) {
                float4 wq = *(const float4*)&W_q[k * DD + 4 * dq];
                float4 wk = *(const float4*)&W_k[k * DD + 4 * dq];
#pragma unroll
                for (int r = 0; r < 2; r++) {
                    float x = S.rows[r][k];
                    aq[r].x = fmaf(x, wq.x, aq[r].x); aq[r].y = fmaf(x, wq.y, aq[r].y);
                    aq[r].z = fmaf(x, wq.z, aq[r].z); aq[r].w = fmaf(x, wq.w, aq[r].w);
                    ak[r].x = fmaf(x, wk.x, ak[r].x); ak[r].y = fmaf(x, wk.y, ak[r].y);
                    ak[r].z = fmaf(x, wk.z, ak[r].z); ak[r].w = fmaf(x, wk.w, ak[r].w);
                }
            }
#pragma unroll
            for (int r = 0; r < 2; r++) { S.redq[kh][r][dq] = aq[r]; S.redk[kh][r][dq] = ak[r]; }
        }
        __syncthreads();
        {   // finalize q,k -> sq,sk
            const int d2 = t & 255, r = t >> 8;
            const int n = n0 + r;
            float qf = b_q[d2], kf = b_k[d2];
#pragma unroll
            for (int kk = 0; kk < 8; kk++) {
                qf += ((const float*)S.redq[kk][r])[d2];
                kf += ((const float*)S.redk[kk][r])[d2];
            }
            float xq = qf * w_attn[d2 & 31];
            float xk = kf * w_attn[32 + (d2 & 31)];
#pragma unroll
            for (int o = 16; o; o >>= 1) { xq += __shfl_xor(xq, o, 32); xk += __shfl_xor(xk, o, 32); }
            if ((d2 & 31) == 0 && n < NN) {
                sq[(size_t)(b * HH + (d2 >> 5)) * NN + n] = xq;
                sk[(size_t)(b * HH + (d2 >> 5)) * NN + n] = xk;
            }
        }
        __syncthreads();
        {   // V sweep (reuse redq)
            float4 av[2];
#pragma unroll
            for (int r = 0; r < 2; r++) av[r] = make_float4(0.f, 0.f, 0.f, 0.f);
            const int kb = kh * 32;
#pragma unroll 4
            for (int k = kb; k < kb + 32; k++) {
                float4 wv = *(const float4*)&W_v[k * DD + 4 * dq];
#pragma unroll
                for (int r = 0; r < 2; r++) {
                    float x = S.rows[r][k];
                    av[r].x = fmaf(x, wv.x, av[r].x); av[r].y = fmaf(x, wv.y, av[r].y);
                    av[r].z = fmaf(x, wv.z, av[r].z); av[r].w = fmaf(x, wv.w, av[r].w);
                }
            }
#pragma unroll
            for (int r = 0; r < 2; r++) S.redq[kh][r][dq] = av[r];
        }
        __syncthreads();
        {
            const int d2 = t & 255, r = t >> 8;
            const int n = n0 + r;
            if (n < NN) {
                float vf = b_v[d2];
#pragma unroll
                for (int kk = 0; kk < 8; kk++) vf += ((const float*)S.redq[kk][r])[d2];
                v[(size_t)(b * NN + n) * DD + d2] = vf;
            }
        }
    } else {
        const int ri = bx - 776;  // 0..63
        if (t < 256) {
            const int c = t;
            const float wec = w_attn[64 + (c & 31)];
#pragma unroll
            for (int rr = 0; rr < 4; rr++) {
                int r = ri * 4 + rr;
                float x = W_e2[(size_t)r * DD + c] * wec;
#pragma unroll
                for (int o = 16; o; o >>= 1) x += __shfl_xor(x, o, 32);
                if ((c & 31) == 0) U[r * HH + (c >> 5)] = x;
            }
            if (ri == 0) {
                float x = b_e2[c] * wec;
#pragma unroll
                for (int o = 16; o; o >>= 1) x += __shfl_xor(x, o, 32);
                if ((c & 31) == 0) ubias[c >> 5] = x;
            }
        }
    }
}

// ============ KMEGA7: R9 champion body, 2 phases + 2 barriers removed =======
// (1) stats computed inline in pass-1 tail (lanes l<16 hold reduced cr/dvv);
// (2) csm reduction folded into out-proj loop (broadcast redc reads).
__global__ __launch_bounds__(256) void kmega7(
    const float* __restrict__ a, const float* __restrict__ bp_t, const float* __restrict__ cp_t,
    const float* __restrict__ var_t, const float* __restrict__ nv,
    const float* __restrict__ v,
    const float* __restrict__ ma, const float* __restrict__ qa,
    const float* __restrict__ mb, const float* __restrict__ qb,
    const float* __restrict__ mc, const float* __restrict__ qc,
    const float* __restrict__ sq, const float* __restrict__ sk,
    const float* __restrict__ ln_g, const float* __restrict__ ln_b,
    const float* __restrict__ U, const float* __restrict__ ubias,
    const float* __restrict__ b_attn,
    const float* __restrict__ W_o, const float* __restrict__ b_o,
    float* __restrict__ attn, float* __restrict__ out) {
    const int it = blockIdx.x, b = blockIdx.y;
    const int i0 = it * 2;
    const int t = threadIdx.x;
    const int w = t >> 6, l = t & 63;
    const int dgp = l >> 4;            // d-group 0..3 (in-wave -> shuffle-reducible)
    const int jp = w * 16 + (l & 15);  // j-pair 0..63 -> j in {2jp, 2jp+1}

    __shared__ float Arow[2][DD];
    __shared__ __attribute__((aligned(8))) float2 lnsm[DD];
    __shared__ __attribute__((aligned(16))) float4 Usm[DD][2];
    __shared__ __attribute__((aligned(8))) float rsm[2][SS], nmm[2][SS], mkm[2][SS], pnm[2][SS];
    __shared__ float skm[HH * NN];
    __shared__ float sqb[2][HH], ubm[HH];
    __shared__ float sc[2][HH][NN + 3];
    __shared__ union { float Vrow[2][DD]; } uv;
    __shared__ __attribute__((aligned(16))) float redc[4][2][DD];

    // ---- stage ----
    {
        int ic0 = i0, ic1 = (i0 + 1 < NN) ? i0 + 1 : NN - 1;
        Arow[0][t] = (ic0 >= 1) ? a[((size_t)b * SS + ic0 - 1) * DD + t] : 0.f;
        Arow[1][t] = (ic1 >= 1) ? a[((size_t)b * SS + ic1 - 1) * DD + t] : 0.f;
        uv.Vrow[0][t] = nv[((size_t)b * NN + ic0) * DD + t];
        uv.Vrow[1][t] = nv[((size_t)b * NN + ic1) * DD + t];
        float2 g; g.x = ln_g[t]; g.y = ln_b[t]; lnsm[t] = g;
        Usm[t][0] = *(const float4*)&U[t * HH];
        Usm[t][1] = *(const float4*)&U[t * HH + 4];
        for (int e = t; e < HH * NN; e += 256) skm[e] = sk[(size_t)b * HH * NN + e];
        if (t < 16) {
            int il = t >> 3, h = t & 7;
            int i = i0 + il; if (i > NN - 1) i = NN - 1;
            sqb[il][h] = sq[(size_t)b * HH * NN + h * NN + i] + b_attn[0];
        }
        if (t < HH) ubm[t] = ubias[t];
    }
    __syncthreads();

    // ---- pass 1 + inline stats: cross = a_{i-1}.bp_j ; dvv = nv_i.var_j ----
    {
        float cr[2][2] = {{0.f, 0.f}, {0.f, 0.f}}, dvv[2][2] = {{0.f, 0.f}, {0.f, 0.f}};
        const float* bc = bp_t + ((size_t)b * DD + dgp * 64) * SS + 2 * jp;
        const float* vc = var_t + ((size_t)b * DD + dgp * 64) * SS + 2 * jp;
#pragma unroll 4
        for (int dd = 0; dd < 64; dd++) {
            float2 bv = *(const float2*)(bc + (size_t)dd * SS);
            float2 vv = *(const float2*)(vc + (size_t)dd * SS);
            const int d = dgp * 64 + dd;
            float A0 = Arow[0][d], A1 = Arow[1][d];
            float V0 = uv.Vrow[0][d], V1 = uv.Vrow[1][d];
            cr[0][0] = fmaf(A0, bv.x, cr[0][0]); cr[0][1] = fmaf(A0, bv.y, cr[0][1]);
            cr[1][0] = fmaf(A1, bv.x, cr[1][0]); cr[1][1] = fmaf(A1, bv.y, cr[1][1]);
            dvv[0][0] = fmaf(V0, vv.x, dvv[0][0]); dvv[0][1] = fmaf(V0, vv.y, dvv[0][1]);
            dvv[1][0] = fmaf(V1, vv.x, dvv[1][0]); dvv[1][1] = fmaf(V1, vv.y, dvv[1][1]);
        }
#pragma unroll
        for (int il = 0; il < 2; il++)
#pragma unroll
            for (int jj = 0; jj < 2; jj++) {
                float c = cr[il][jj], d2 = dvv[il][jj];
                c += __shfl_xor(c, 16); c += __shfl_xor(c, 32);
                d2 += __shfl_xor(d2, 16); d2 += __shfl_xor(d2, 32);
                cr[il][jj] = c; dvv[il][jj] = d2;
            }
        if (l < 16) {
            const int j0 = 2 * jp, j1 = j0 + 1;
#pragma unroll
            for (int il = 0; il < 2; il++) {
                int i = i0 + il; if (i > NN - 1) i = NN - 1;
                float rs0, nm0, mk0, pn0, rs1, nm1, mk1, pn1;
                if (i == 0) {
                    float mu0 = mc[b * SS + j0], q20 = qc[b * SS + j0];
                    rs0 = rsqrtf(q20 - mu0 * mu0 + LN_EPS); nm0 = -mu0 * rs0; mk0 = 1.f; pn0 = 0.f;
                    float mu1 = mc[b * SS + j1], q21 = qc[b * SS + j1];
                    rs1 = rsqrtf(q21 - mu1 * mu1 + LN_EPS); nm1 = -mu1 * rs1; mk1 = 1.f; pn1 = 0.f;
                } else {
                    float muA = ma[b * SS + i - 1], qA = qa[b * SS + i - 1];
                    {
                        float muB = mb[b * SS + j0], qB = qb[b * SS + j0];
                        float mu = muA + muB;
                        float var = qA + qB + 2.f * cr[il][0] * (1.f / DD) - mu * mu;
                        rs0 = rsqrtf(var + LN_EPS); nm0 = -mu * rs0;
                        mk0 = ((i - 1) != j0 && dvv[il][0] > 0.f) ? 1.f : 0.f;
                        pn0 = (mk0 == 0.f) ? -1e9f : 0.f;
                    }
                    {
                        float muB = mb[b * SS + j1], qB = qb[b * SS + j1];
                        float mu = muA + muB;
                        float var = qA + qB + 2.f * cr[il][1] * (1.f / DD) - mu * mu;
                        rs1 = rsqrtf(var + LN_EPS); nm1 = -mu * rs1;
                        mk1 = ((i - 1) != j1 && dvv[il][1] > 0.f) ? 1.f : 0.f;
                        pn1 = (mk1 == 0.f) ? -1e9f : 0.f;
                    }
                }
                rsm[il][j0] = rs0; nmm[il][j0] = nm0; mkm[il][j0] = mk0; pnm[il][j0] = pn0;
                rsm[il][j1] = rs1; nmm[il][j1] = nm1; mkm[il][j1] = mk1; pnm[il][j1] = pn1;
            }
        }
    }
    __syncthreads();
    // ---- pass 2: LN + relu + U-dot (shared B panel; shuffle-reduced) ----
    float acc[2][HH][2];
#pragma unroll
    for (int il = 0; il < 2; il++)
#pragma unroll
        for (int h = 0; h < HH; h++) { acc[il][h][0] = 0.f; acc[il][h][1] = 0.f; }
    {
        const float* Bb = bp_t + ((size_t)b * DD + dgp * 64) * SS + 2 * jp;
        float2 r0 = *(const float2*)&rsm[0][2 * jp];
        float2 n0 = *(const float2*)&nmm[0][2 * jp];
        float2 r1 = *(const float2*)&rsm[1][2 * jp];
        float2 n1 = *(const float2*)&nmm[1][2 * jp];
        if (i0 != 0) {
#pragma unroll 4
            for (int dd = 0; dd < 64; dd++) {
                const int d = dgp * 64 + dd;
                float2 bv = *(const float2*)(Bb + (size_t)dd * SS);
                float A0 = Arow[0][d], A1 = Arow[1][d];
                float2 gb = lnsm[d];
                float4 u0 = Usm[d][0], u1 = Usm[d][1];
                float y0 = fmaf(A0 + bv.x, r0.x, n0.x); y0 = fmaf(y0, gb.x, gb.y);
                float y1 = fmaf(A0 + bv.y, r0.y, n0.y); y1 = fmaf(y1, gb.x, gb.y);
                float e0 = fmaxf(y0, 0.f), e1 = fmaxf(y1, 0.f);
                float z0 = fmaf(A1 + bv.x, r1.x, n1.x); z0 = fmaf(z0, gb.x, gb.y);
                float z1 = fmaf(A1 + bv.y, r1.y, n1.y); z1 = fmaf(z1, gb.x, gb.y);
                float f0 = fmaxf(z0, 0.f), f1 = fmaxf(z1, 0.f);
                acc[0][0][0] = fmaf(e0, u0.x, acc[0][0][0]); acc[0][0][1] = fmaf(e1, u0.x, acc[0][0][1]);
                acc[0][1][0] = fmaf(e0, u0.y, acc[0][1][0]); acc[0][1][1] = fmaf(e1, u0.y, acc[0][1][1]);
                acc[0][2][0] = fmaf(e0, u0.z, acc[0][2][0]); acc[0][2][1] = fmaf(e1, u0.z, acc[0][2][1]);
                acc[0][3][0] = fmaf(e0, u0.w, acc[0][3][0]); acc[0][3][1] = fmaf(e1, u0.w, acc[0][3][1]);
                acc[0][4][0] = fmaf(e0, u1.x, acc[0][4][0]); acc[0][4][1] = fmaf(e1, u1.x, acc[0][4][1]);
                acc[0][5][0] = fmaf(e0, u1.y, acc[0][5][0]); acc[0][5][1] = fmaf(e1, u1.y, acc[0][5][1]);
                acc[0][6][0] = fmaf(e0, u1.z, acc[0][6][0]); acc[0][6][1] = fmaf(e1, u1.z, acc[0][6][1]);
                acc[0][7][0] = fmaf(e0, u1.w, acc[0][7][0]); acc[0][7][1] = fmaf(e1, u1.w, acc[0][7][1]);
                acc[1][0][0] = fmaf(f0, u0.x, acc[1][0][0]); acc[1][0][1] = fmaf(f1, u0.x, acc[1][0][1]);
                acc[1][1][0] = fmaf(f0, u0.y, acc[1][1][0]); acc[1][1][1] = fmaf(f1, u0.y, acc[1][1][1]);
                acc[1][2][0] = fmaf(f0, u0.z, acc[1][2][0]); acc[1][2][1] = fmaf(f1, u0.z, acc[1][2][1]);
                acc[1][3][0] = fmaf(f0, u0.w, acc[1][3][0]); acc[1][3][1] = fmaf(f1, u0.w, acc[1][3][1]);
                acc[1][4][0] = fmaf(f0, u1.x, acc[1][4][0]); acc[1][4][1] = fmaf(f1, u1.x, acc[1][4][1]);
                acc[1][5][0] = fmaf(f0, u1.y, acc[1][5][0]); acc[1][5][1] = fmaf(f1, u1.y, acc[1][5][1]);
                acc[1][6][0] = fmaf(f0, u1.z, acc[1][6][0]); acc[1][6][1] = fmaf(f1, u1.z, acc[1][6][1]);
                acc[1][7][0] = fmaf(f0, u1.w, acc[1][7][0]); acc[1][7][1] = fmaf(f1, u1.w, acc[1][7][1]);
            }
        } else {
            const float* Bc = cp_t + ((size_t)b * DD + dgp * 64) * SS + 2 * jp;
#pragma unroll 4
            for (int dd = 0; dd < 64; dd++) {
                const int d = dgp * 64 + dd;
                float2 bA = *(const float2*)(Bc + (size_t)dd * SS);
                float2 bB = *(const float2*)(Bb + (size_t)dd * SS);
                float A0 = Arow[0][d], A1 = Arow[1][d];
                float2 gb = lnsm[d];
                float4 u0 = Usm[d][0], u1 = Usm[d][1];
                float y0 = fmaf(A0 + bA.x, r0.x, n0.x); y0 = fmaf(y0, gb.x, gb.y);
                float y1 = fmaf(A0 + bA.y, r0.y, n0.y); y1 = fmaf(y1, gb.x, gb.y);
                float e0 = fmaxf(y0, 0.f), e1 = fmaxf(y1, 0.f);
                float z0 = fmaf(A1 + bB.x, r1.x, n1.x); z0 = fmaf(z0, gb.x, gb.y);
                float z1 = fmaf(A1 + bB.y, r1.y, n1.y); z1 = fmaf(z1, gb.x, gb.y);
                float f0 = fmaxf(z0, 0.f), f1 = fmaxf(z1, 0.f);
                acc[0][0][0] = fmaf(e0, u0.x, acc[0][0][0]); acc[0][0][1] = fmaf(e1, u0.x, acc[0][0][1]);
                acc[0][1][0] = fmaf(e0, u0.y, acc[0][1][0]); acc[0][1][1] = fmaf(e1, u0.y, acc[0][1][1]);
                acc[0][2][0] = fmaf(e0, u0.z, acc[0][2][0]); acc[0][2][1] = fmaf(e1, u0.z, acc[0][2][1]);
                acc[0][3][0] = fmaf(e0, u0.w, acc[0][3][0]); acc[0][3][1] = fmaf(e1, u0.w, acc[0][3][1]);
                acc[0][4][0] = fmaf(e0, u1.x, acc[0][4][0]); acc[0][4][1] = fmaf(e1, u1.x, acc[0][4][1]);
                acc[0][5][0] = fmaf(e0, u1.y, acc[0][5][0]); acc[0][5][1] = fmaf(e1, u1.y, acc[0][5][1]);
                acc[0][6][0] = fmaf(e0, u1.z, acc[0][6][0]); acc[0][6][1] = fmaf(e1, u1.z, acc[0][6][1]);
                acc[0][7][0] = fmaf(e0, u1.w, acc[0][7][0]); acc[0][7][1] = fmaf(e1, u1.w, acc[0][7][1]);
                acc[1][0][0] = fmaf(f0, u0.x, acc[1][0][0]); acc[1][0][1] = fmaf(f1, u0.x, acc[1][0][1]);
                acc[1][1][0] = fmaf(f0, u0.y, acc[1][1][0]); acc[1][1][1] = fmaf(f1, u0.y, acc[1][1][1]);
                acc[1][2][0] = fmaf(f0, u0.z, acc[1][2][0]); acc[1][2][1] = fmaf(f1, u0.z, acc[1][2][1]);
                acc[1][3][0] = fmaf(f0, u0.w, acc[1][3][0]); acc[1][3][1] = fmaf(f1, u0.w, acc[1][3][1]);
                acc[1][4][0] = fmaf(f0, u1.x, acc[1][4][0]); acc[1][4][1] = fmaf(f1, u1.x, acc[1][4][1]);
                acc[1][5][0] = fmaf(f0, u1.y, acc[1][5][0]); acc[1][5][1] = fmaf(f1, u1.y, acc[1][5][1]);
                acc[1][6][0] = fmaf(f0, u1.z, acc[1][6][0]); acc[1][6][1] = fmaf(f1, u1.z, acc[1][6][1]);
                acc[1][7][0] = fmaf(f0, u1.w, acc[1][7][0]); acc[1][7][1] = fmaf(f1, u1.w, acc[1][7][1]);
            }
        }
    }
    // in-wave reduce over d-groups, then assemble scores directly
#pragma unroll
    for (int il = 0; il < 2; il++)
#pragma unroll
        for (int h = 0; h < HH; h++) {
            float s0 = acc[il][h][0], s1 = acc[il][h][1];
            s0 += __shfl_xor(s0, 16); s0 += __shfl_xor(s0, 32);
            s1 += __shfl_xor(s1, 16); s1 += __shfl_xor(s1, 32);
            acc[il][h][0] = s0; acc[il][h][1] = s1;
        }
    if (l < 16) {
        const int j0 = 2 * jp, j1 = j0 + 1;
#pragma unroll
        for (int il = 0; il < 2; il++) {
            float mk0 = mkm[il][j0], pn0 = pnm[il][j0];
            float mk1 = mkm[il][j1], pn1 = pnm[il][j1];
#pragma unroll
            for (int h = 0; h < HH; h++) {
                sc[il][h][1 + j0] = sqb[il][h] + skm[h * NN + 1 + j0] + (acc[il][h][0] + ubm[h]) * mk0 + pn0;
                sc[il][h][1 + j1] = sqb[il][h] + skm[h * NN + 1 + j1] + (acc[il][h][1] + ubm[h]) * mk1 + pn1;
            }
        }
    }
    if (t < 16) { int il = t >> 3, h = t & 7; sc[il][h][0] = sqb[il][h] + skm[h * NN] - 1e9f; }
    __syncthreads();
    // ---- softmax: normalize sc in place + write attn ----
    {
        const int row = t >> 4, ll = t & 15;
        const int il = row >> 3, h = row & 7;
        const int i = i0 + il;
        float m = -INFINITY;
        for (int j = ll; j < NN; j += 16) m = fmaxf(m, sc[il][h][j]);
#pragma unroll
        for (int o = 8; o; o >>= 1) m = fmaxf(m, __shfl_xor(m, o, 16));
        float s = 0.f;
        float ev[9];
        int cnt = 0;
        for (int j = ll; j < NN; j += 16) { float e = __expf(sc[il][h][j] - m); ev[cnt++] = e; s += e; }
#pragma unroll
        for (int o = 8; o; o >>= 1) s += __shfl_xor(s, o, 16);
        float inv = 1.f / s;
        float* arow = attn + (((size_t)b * HH + h) * NN + i) * NN;
        cnt = 0;
        for (int j = ll; j < NN; j += 16) {
            float p = ev[cnt++] * inv;
            sc[il][h][j] = p;
            if (i < NN) arow[j] = p;
        }
    }
    __syncthreads();
    // ---- ctx = p @ v (thread = d-quad x j-group) ----
    {
        const int dq = t & 63, jg = t >> 6;
        const int h = dq >> 3;
        float ca[2][4] = {{0.f, 0.f, 0.f, 0.f}, {0.f, 0.f, 0.f, 0.f}};
#pragma unroll 4
        for (int jj = 0; jj < 33; jj++) {
            int j = jg * 33 + jj;
            if (j < NN) {
                float4 vv = *(const float4*)&v[((size_t)b * NN + j) * DD + 4 * dq];
                float p0 = sc[0][h][j], p1 = sc[1][h][j];
                ca[0][0] = fmaf(p0, vv.x, ca[0][0]); ca[0][1] = fmaf(p0, vv.y, ca[0][1]);
                ca[0][2] = fmaf(p0, vv.z, ca[0][2]); ca[0][3] = fmaf(p0, vv.w, ca[0][3]);
                ca[1][0] = fmaf(p1, vv.x, ca[1][0]); ca[1][1] = fmaf(p1, vv.y, ca[1][1]);
                ca[1][2] = fmaf(p1, vv.z, ca[1][2]); ca[1][3] = fmaf(p1, vv.w, ca[1][3]);
            }
        }
#pragma unroll
        for (int il = 0; il < 2; il++) {
            float4 wv; wv.x = ca[il][0]; wv.y = ca[il][1]; wv.z = ca[il][2]; wv.w = ca[il][3];
            *(float4*)&redc[jg][il][4 * dq] = wv;
        }
    }
    __syncthreads();
    // ---- out = ctx @ W_o + b_o (csm reduce folded in; broadcast redc reads) -
    {
        const int cq = t & 63, kg = t >> 6;
        float o[2][4] = {{0.f, 0.f, 0.f, 0.f}, {0.f, 0.f, 0.f, 0.f}};
#pragma unroll 4
        for (int kk = 0; kk < 64; kk++) {
            int k = kg * 64 + kk;
            float4 wv = *(const float4*)&W_o[(size_t)k * DD + 4 * cq];
            float c0 = (redc[0][0][k] + redc[1][0][k]) + (redc[2][0][k] + redc[3][0][k]);
            float c1 = (redc[0][1][k] + redc[1][1][k]) + (redc[2][1][k] + redc[3][1][k]);
            o[0][0] = fmaf(c0, wv.x, o[0][0]); o[0][1] = fmaf(c0, wv.y, o[0][1]);
            o[0][2] = fmaf(c0, wv.z, o[0][2]); o[0][3] = fmaf(c0, wv.w, o[0][3]);
            o[1][0] = fmaf(c1, wv.x, o[1][0]); o[1][1] = fmaf(c1, wv.y, o[1][1]);
            o[1][2] = fmaf(c1, wv.z, o[1][2]); o[1][3] = fmaf(c1, wv.w, o[1][3]);
        }
        __syncthreads();  // all redc reads done before reuse
#pragma unroll
        for (int il = 0; il < 2; il++) {
            float4 wv; wv.x = o[il][0]; wv.y = o[il][1]; wv.z = o[il][2]; wv.w = o[il][3];
            *(float4*)&redc[kg][il][4 * cq] = wv;
        }
    }
    __syncthreads();
    {
        float bo = b_o[t];
#pragma unroll
        for (int il = 0; il < 2; il++) {
            int i = i0 + il;
            if (i < NN) {
                float s = (redc[0][il][t] + redc[1][il][t])
                        + (redc[2][il][t] + redc[3][il][t]) + bo;
                out[((size_t)b * NN + i) * DD + t] = s;
            }
        }
    }
}

extern "C" void kernel_launch(void* const* d_in, const int* in_sizes, int n_in,
                              void* d_out, int out_size, void* d_ws, size_t ws_size,
                              hipStream_t stream) {
    const float* desc   = (const float*)d_in[0];
    const float* nv     = (const float*)d_in[1];
    const float* W_gt   = (const float*)d_in[2];
    const float* b_gt   = (const float*)d_in[3];
    // d_in[4] topo_bias unused: sigmoid(x)>0 always, so adjacency sign = sample_sim sign
    const float* W_q    = (const float*)d_in[5];
    const float* b_q    = (const float*)d_in[6];
    const float* W_k    = (const float*)d_in[7];
    const float* b_k    = (const float*)d_in[8];
    const float* W_v    = (const float*)d_in[9];
    const float* b_v    = (const float*)d_in[10];
    const float* W_e1   = (const float*)d_in[11];
    const float* b_e1   = (const float*)d_in[12];
    const float* ln_g   = (const float*)d_in[13];
    const float* ln_b   = (const float*)d_in[14];
    const float* W_e2   = (const float*)d_in[15];
    const float* b_e2   = (const float*)d_in[16];
    const float* w_attn = (const float*)d_in[17];
    const float* b_attn = (const float*)d_in[18];
    const float* W_o    = (const float*)d_in[19];
    const float* b_o    = (const float*)d_in[20];

    float* ws   = (float*)d_ws;
    float* a    = ws + OFF_A;
    float* bp_t = ws + OFF_BPT;
    float* cp_t = ws + OFF_CPT;
    float* vart = ws + OFF_VART;
    float* v    = ws + OFF_V;
    float* sq   = ws + OFF_SQ;
    float* sk   = ws + OFF_SK;
    float* ma   = ws + OFF_MA;
    float* qa   = ws + OFF_QA;
    float* mb   = ws + OFF_MB;
    float* qb   = ws + OFF_QB;
    float* mc   = ws + OFF_MC;
    float* qc   = ws + OFF_QC;
    float* U    = ws + OFF_U;
    float* ub   = ws + OFF_UB;

    float* out  = (float*)d_out;
    float* attn = (float*)d_out + (size_t)BB * NN * DD;

    // L1: 256 projA + 520 qkv + 64 U-fold = 840 blocks
    ka_all<<<dim3(840), dim3(512), 0, stream>>>(
        desc, nv, W_gt, b_gt, W_e1, b_e1, W_q, b_q, W_k, b_k, W_v, b_v,
        W_e2, b_e2, w_attn,
        a, bp_t, cp_t, vart, v, sq, sk, ma, qa, mb, qb, mc, qc, U, ub);
    // L2: everything else, one kernel (gram+stats inline + scores + softmax +
    // ctx + out with folded reduce)
    kmega7<<<dim3(65, BB), dim3(256), 0, stream>>>(
        a, bp_t, cp_t, vart, nv, v, ma, qa, mb, qb, mc, qc, sq, sk,
        ln_g, ln_b, U, ub, b_attn, W_o, b_o, attn, out);
}